// Round 1
// baseline (590.517 us; speedup 1.0000x reference)
//
#include <hip/hip_runtime.h>
#include <type_traits>

typedef __bf16 bf16_t;
typedef __bf16 bf16x4 __attribute__((ext_vector_type(4)));
typedef __bf16 bf16x8 __attribute__((ext_vector_type(8)));
typedef float f32x4 __attribute__((ext_vector_type(4)));

// Problem constants (B, N, L, D, H) = (8, 128, 4096, 1024, 16)
constexpr int CB = 8, CN = 128, CL = 4096, CD = 1024, CH = 16, CDh = 64;

__device__ __forceinline__ bf16x4 cvt4(float4 v) {
  bf16x4 r;
  r[0] = (__bf16)v.x; r[1] = (__bf16)v.y; r[2] = (__bf16)v.z; r[3] = (__bf16)v.w;
  return r;
}

// C[M,N] = A[M,K] @ Bw[N,K]^T  (nn.Linear semantics). A is f32 or bf16,
// Bw is f32 (weights), C is f32 or bf16. 128x128 tile, BK=32, 4 waves (2x2),
// each wave 4x4 fragments of mfma_f32_16x16x32_bf16. f32->bf16 cvt fused
// into reg-staged LDS writes (lets us pad LDS rows: +8 shorts kills the
// power-of-2 bank stride).
template<bool A_IS_F32, bool C_IS_F32>
__global__ __launch_bounds__(256)
void gemm_bt(const void* __restrict__ Ap, const float* __restrict__ Bw,
             void* __restrict__ Cp, int M, int N, int K) {
  (void)M;
  __shared__ bf16_t As[128][40];
  __shared__ bf16_t Bs[128][40];
  const int t = (int)threadIdx.x;
  const int lane = t & 63, wv = t >> 6;
  const int wm = (wv >> 1) * 64, wn = (wv & 1) * 64;
  const int brow = (int)blockIdx.y * 128, bcol = (int)blockIdx.x * 128;
  const int fr = lane & 15, fk = (lane >> 4) * 8;

  const f32x4 z = {0.f, 0.f, 0.f, 0.f};
  f32x4 acc[4][4];
#pragma unroll
  for (int m = 0; m < 4; ++m)
#pragma unroll
    for (int n = 0; n < 4; ++n) acc[m][n] = z;

  for (int k0 = 0; k0 < K; k0 += 32) {
    // ---- stage A tile (128 x 32) ----
    if constexpr (A_IS_F32) {
      const float* A = (const float*)Ap;
      const int tr = t >> 3, tc = (t & 7) * 4;  // 8 thr/row, 32 rows/pass
#pragma unroll
      for (int p = 0; p < 4; ++p) {
        const int r = p * 32 + tr;
        float4 v = *reinterpret_cast<const float4*>(A + (size_t)(brow + r) * K + k0 + tc);
        *reinterpret_cast<bf16x4*>(&As[r][tc]) = cvt4(v);
      }
    } else {
      const bf16_t* A = (const bf16_t*)Ap;
      const int tr = t >> 2, tc = (t & 3) * 8;  // 4 thr/row, 64 rows/pass
#pragma unroll
      for (int p = 0; p < 2; ++p) {
        const int r = p * 64 + tr;
        *reinterpret_cast<int4*>(&As[r][tc]) =
            *reinterpret_cast<const int4*>(A + (size_t)(brow + r) * K + k0 + tc);
      }
    }
    // ---- stage B tile (128 x 32), always f32 weights ----
    {
      const int tr = t >> 3, tc = (t & 7) * 4;
#pragma unroll
      for (int p = 0; p < 4; ++p) {
        const int r = p * 32 + tr;
        float4 v = *reinterpret_cast<const float4*>(Bw + (size_t)(bcol + r) * K + k0 + tc);
        *reinterpret_cast<bf16x4*>(&Bs[r][tc]) = cvt4(v);
      }
    }
    __syncthreads();
    bf16x8 af[4], bfr[4];
#pragma unroll
    for (int m = 0; m < 4; ++m)
      af[m] = *reinterpret_cast<const bf16x8*>(&As[wm + m * 16 + fr][fk]);
#pragma unroll
    for (int n = 0; n < 4; ++n)
      bfr[n] = *reinterpret_cast<const bf16x8*>(&Bs[wn + n * 16 + fr][fk]);
#pragma unroll
    for (int m = 0; m < 4; ++m)
#pragma unroll
      for (int n = 0; n < 4; ++n)
        acc[m][n] = __builtin_amdgcn_mfma_f32_16x16x32_bf16(af[m], bfr[n], acc[m][n], 0, 0, 0);
    __syncthreads();
  }

  // epilogue: C/D layout col=lane&15, row=(lane>>4)*4+reg  [m89-verified]
  const int rb = (lane >> 4) * 4;
#pragma unroll
  for (int m = 0; m < 4; ++m)
#pragma unroll
    for (int n = 0; n < 4; ++n)
#pragma unroll
      for (int r = 0; r < 4; ++r) {
        const int row = brow + wm + m * 16 + rb + r;
        const int col = bcol + wn + n * 16 + fr;
        if constexpr (C_IS_F32)
          ((float*)Cp)[(size_t)row * N + col] = acc[m][n][r];
        else
          ((bf16_t*)Cp)[(size_t)row * N + col] = (__bf16)acc[m][n][r];
      }
}

// Fused inverted attention. One block (4 waves) per (b,h).
// S = scale * Qh Kh^T   (S: 128 x Ltile, Ltile = 64)
// softmax over the N=128 axis (exact per l-column, fully in-tile),
// P -> LDS (bf16), PV via MFMA with V^T in LDS + ones-row (col 64 of the
// output = row-sum R[n], the L1-renorm denominator) accumulated over L.
__global__ __launch_bounds__(256)
void attn_inv(const bf16_t* __restrict__ qh, const bf16_t* __restrict__ kh,
              const bf16_t* __restrict__ vh, bf16_t* __restrict__ ao) {
  const int bh = (int)blockIdx.x;
  const int b = bh >> 4, h = bh & 15;

  __shared__ bf16_t Qs[128][72];
  __shared__ bf16_t Ks[64][72];
  __shared__ bf16_t Vt[80][72];  // rows 0..63 = V^T(c,l), row 64 = ones, 65..79 = 0
  __shared__ bf16_t Ps[128][72];

  const int t = (int)threadIdx.x;
  const int lane = t & 63, w = t >> 6;
  const int fr = lane & 15, fq = lane >> 4;

  // load Q tile (128 x 64) once
  const bf16_t* qb = qh + (size_t)(b * CN) * CD + h * CDh;
#pragma unroll
  for (int p = 0; p < 4; ++p) {
    const int j = p * 256 + t;
    const int r = j >> 3, cc = (j & 7) * 8;
    *reinterpret_cast<int4*>(&Qs[r][cc]) =
        *reinterpret_cast<const int4*>(qb + (size_t)r * CD + cc);
  }
  // init ones/zero rows of Vt (never overwritten)
#pragma unroll
  for (int p = 0; p < 4; ++p) {
    const int j = p * 256 + t;
    const int r = 64 + (j >> 6), c = j & 63;
    Vt[r][c] = (r == 64) ? (__bf16)1.0f : (__bf16)0.0f;
  }

  const f32x4 z = {0.f, 0.f, 0.f, 0.f};
  f32x4 acc[2][5];
#pragma unroll
  for (int m = 0; m < 2; ++m)
#pragma unroll
    for (int n = 0; n < 5; ++n) acc[m][n] = z;

  for (int l0 = 0; l0 < CL; l0 += 64) {
    __syncthreads();  // protect Ks/Vt from previous iteration's PV readers
    const bf16_t* kb = kh + (size_t)(b * CL + l0) * CD + h * CDh;
    const bf16_t* vb = vh + (size_t)(b * CL + l0) * CD + h * CDh;
#pragma unroll
    for (int p = 0; p < 2; ++p) {
      const int j = p * 256 + t;
      const int r = j >> 3, cc = (j & 7) * 8;
      *reinterpret_cast<int4*>(&Ks[r][cc]) =
          *reinterpret_cast<const int4*>(kb + (size_t)r * CD + cc);
      int4 vv = *reinterpret_cast<const int4*>(vb + (size_t)r * CD + cc);
      const bf16_t* hp = reinterpret_cast<const bf16_t*>(&vv);
#pragma unroll
      for (int i = 0; i < 8; ++i) Vt[cc + i][r] = hp[i];  // transpose
    }
    __syncthreads();

    // QK^T: wave w owns l-columns [16w, 16w+16)
    f32x4 s[8];
#pragma unroll
    for (int m = 0; m < 8; ++m) s[m] = z;
#pragma unroll
    for (int ks = 0; ks < 2; ++ks) {
      bf16x8 bk = *reinterpret_cast<const bf16x8*>(&Ks[w * 16 + fr][ks * 32 + fq * 8]);
#pragma unroll
      for (int m = 0; m < 8; ++m) {
        bf16x8 aq = *reinterpret_cast<const bf16x8*>(&Qs[m * 16 + fr][ks * 32 + fq * 8]);
        s[m] = __builtin_amdgcn_mfma_f32_16x16x32_bf16(aq, bk, s[m], 0, 0, 0);
      }
    }

    // softmax over n (exact: whole column resident). scale = D^-0.5 = 1/32
    float p[8][4];
    float mx = -3.0e38f;
#pragma unroll
    for (int m = 0; m < 8; ++m)
#pragma unroll
      for (int r = 0; r < 4; ++r) {
        const float x = s[m][r] * 0.03125f;
        p[m][r] = x;
        mx = fmaxf(mx, x);
      }
    mx = fmaxf(mx, __shfl_xor(mx, 16));
    mx = fmaxf(mx, __shfl_xor(mx, 32));
    float sum = 0.f;
#pragma unroll
    for (int m = 0; m < 8; ++m)
#pragma unroll
      for (int r = 0; r < 4; ++r) {
        const float e = __expf(p[m][r] - mx);
        p[m][r] = e;
        sum += e;
      }
    sum += __shfl_xor(sum, 16);
    sum += __shfl_xor(sum, 32);
    const float inv = 1.0f / sum;
    const int pcol = w * 16 + fr;
#pragma unroll
    for (int m = 0; m < 8; ++m)
#pragma unroll
      for (int r = 0; r < 4; ++r)
        Ps[m * 16 + fq * 4 + r][pcol] = (__bf16)(p[m][r] * inv);
    __syncthreads();

    // PV: wave w owns output rows [32w, 32w+32); 5th n-frag = ones col -> R[n]
#pragma unroll
    for (int ks = 0; ks < 2; ++ks) {
      bf16x8 pa[2];
#pragma unroll
      for (int m = 0; m < 2; ++m)
        pa[m] = *reinterpret_cast<const bf16x8*>(&Ps[w * 32 + m * 16 + fr][ks * 32 + fq * 8]);
#pragma unroll
      for (int n = 0; n < 5; ++n) {
        bf16x8 bv = *reinterpret_cast<const bf16x8*>(&Vt[n * 16 + fr][ks * 32 + fq * 8]);
#pragma unroll
        for (int m = 0; m < 2; ++m)
          acc[m][n] = __builtin_amdgcn_mfma_f32_16x16x32_bf16(pa[m], bv, acc[m][n], 0, 0, 0);
      }
    }
  }

  // epilogue: out = acc / R  (R lives in acc[m][4], lanes with fr==0)
  bf16_t* ob = ao + (size_t)(b * CN) * CD + h * CDh;
#pragma unroll
  for (int m = 0; m < 2; ++m)
#pragma unroll
    for (int r = 0; r < 4; ++r) {
      const float R = __shfl(acc[m][4][r], lane & 48);  // broadcast from fr==0 lane
      const float invr = 1.0f / R;
      const int row = w * 32 + m * 16 + fq * 4 + r;
#pragma unroll
      for (int n = 0; n < 4; ++n) {
        const int col = n * 16 + fr;
        ob[(size_t)row * CD + col] = (__bf16)(acc[m][n][r] * invr);
      }
    }
}

extern "C" void kernel_launch(void* const* d_in, const int* in_sizes, int n_in,
                              void* d_out, int out_size, void* d_ws, size_t ws_size,
                              hipStream_t stream) {
  (void)in_sizes; (void)n_in; (void)out_size;
  const float* q  = (const float*)d_in[0];
  const float* k  = (const float*)d_in[1];
  const float* v  = (const float*)d_in[2];
  const float* Wq = (const float*)d_in[3];
  const float* Wk = (const float*)d_in[4];
  const float* Wv = (const float*)d_in[5];
  const float* Wo = (const float*)d_in[6];
  float* out = (float*)d_out;

  // workspace layout (bf16): qh 2MB | kh 64MB | vh 64MB | attn_out 2MB
  const size_t QH_OFF = 0;
  const size_t KH_OFF = (size_t)2 << 20;
  const size_t VH_OFF = KH_OFF + ((size_t)64 << 20);
  const size_t AO_OFF = VH_OFF + ((size_t)64 << 20);
  const size_t NEED   = AO_OFF + ((size_t)2 << 20);
  if (ws_size < NEED) return;  // would corrupt; fail validation loudly instead

  char* ws = (char*)d_ws;
  bf16_t* qh = (bf16_t*)(ws + QH_OFF);
  bf16_t* kh = (bf16_t*)(ws + KH_OFF);
  bf16_t* vh = (bf16_t*)(ws + VH_OFF);
  bf16_t* ao = (bf16_t*)(ws + AO_OFF);

  const int M_q = CB * CN;   // 1024
  const int M_kv = CB * CL;  // 32768

  gemm_bt<true,  false><<<dim3(CD / 128, M_q / 128),  256, 0, stream>>>(q, Wq, qh, M_q,  CD, CD);
  gemm_bt<true,  false><<<dim3(CD / 128, M_kv / 128), 256, 0, stream>>>(k, Wk, kh, M_kv, CD, CD);
  gemm_bt<true,  false><<<dim3(CD / 128, M_kv / 128), 256, 0, stream>>>(v, Wv, vh, M_kv, CD, CD);
  attn_inv<<<dim3(CB * CH), 256, 0, stream>>>(qh, kh, vh, ao);
  gemm_bt<false, true ><<<dim3(CD / 128, M_q / 128),  256, 0, stream>>>(ao, Wo, out, M_q, CD, CD);
}

// Round 2
// 463.532 us; speedup vs baseline: 1.2740x; 1.2740x over previous
//
#include <hip/hip_runtime.h>
#include <stdint.h>

typedef __bf16 bf16_t;
typedef __bf16 bf16x4 __attribute__((ext_vector_type(4)));
typedef __bf16 bf16x8 __attribute__((ext_vector_type(8)));
typedef float f32x4 __attribute__((ext_vector_type(4)));
typedef unsigned int u32;

// Problem constants (B, N, L, D, H) = (8, 128, 4096, 1024, 16)
constexpr int CB = 8, CN = 128, CL = 4096, CD = 1024, CH = 16, CDh = 64;

__device__ __forceinline__ bf16x4 cvt4(float4 v) {
  bf16x4 r;
  r[0] = (__bf16)v.x; r[1] = (__bf16)v.y; r[2] = (__bf16)v.z; r[3] = (__bf16)v.w;
  return r;
}
__device__ __forceinline__ bf16x8 cvt8v(f32x4 lo, f32x4 hi) {
  bf16x8 r;
#pragma unroll
  for (int i = 0; i < 4; ++i) { r[i] = (__bf16)lo[i]; r[i + 4] = (__bf16)hi[i]; }
  return r;
}

// async global->LDS, 16 B per lane. LDS dest is wave-uniform base + lane*16.
__device__ __forceinline__ void async16(void* lds, const void* g) {
  __builtin_amdgcn_global_load_lds(
      (const __attribute__((address_space(1))) u32*)g,
      (__attribute__((address_space(3))) u32*)lds, 16, 0, 0);
}

// f32 -> bf16 elementwise (for weights), n4 = elems/4
__global__ __launch_bounds__(256) void cvt_f32_bf16(const float* __restrict__ in,
                                                    bf16_t* __restrict__ outp, int n4) {
  int i = (int)blockIdx.x * 256 + (int)threadIdx.x;
  if (i < n4) {
    float4 v = reinterpret_cast<const float4*>(in)[i];
    reinterpret_cast<bf16x4*>(outp)[i] = cvt4(v);
  }
}

// ---------------------------------------------------------------------------
// DMA-staged GEMM: C[M,N] = A[M,K] @ Wb[N,K]^T.  A f32 (AF32) or bf16.
// Wb always bf16.  128x128 tile, BK=32, 4 waves, global_load_lds width-16,
// source-side XOR swizzle (linear DMA dest + pre-swizzled global src + swizzled
// ds_read).  A-f32 rows = 128B: phys = logical ^ ((row&7)<<4)  (8-slot spread).
// bf16 rows = 64B:  phys = logical ^ (((row>>1)&3)<<4)         (8-slot w/ parity).
// Grid: 1D nwg = mblocks*(N/128), nwg%8==0. XCD swizzle: each XCD owns an
// N-column stripe and sweeps M (W stays L2-resident, A panel L3-resident).
// ---------------------------------------------------------------------------
template<bool AF32, bool CF32>
__global__ __launch_bounds__(256)
void gemm_dma(const void* __restrict__ Ap, const bf16_t* __restrict__ Bw,
              void* __restrict__ Cp, int mblocks, int N, int K) {
  __shared__ __attribute__((aligned(16))) char AsB[AF32 ? 16384 : 8192];
  __shared__ __attribute__((aligned(16))) char BsB[8192];

  const int t = (int)threadIdx.x;
  const int lane = t & 63, wv = t >> 6;
  const int bid = (int)blockIdx.x;
  const int cpx = (int)gridDim.x >> 3;
  const int wid = (bid & 7) * cpx + (bid >> 3);
  const int brow = (wid % mblocks) * 128;
  const int bcol = (wid / mblocks) * 128;
  const int wm = (wv >> 1) * 64, wn = (wv & 1) * 64;
  const int fr = lane & 15, fq = lane >> 4;

  const float*  Af = (const float*)Ap;
  const bf16_t* Ab = (const bf16_t*)Ap;

  const f32x4 z = {0.f, 0.f, 0.f, 0.f};
  f32x4 acc[4][4];
#pragma unroll
  for (int m = 0; m < 4; ++m)
#pragma unroll
    for (int n = 0; n < 4; ++n) acc[m][n] = z;

  for (int k0 = 0; k0 < K; k0 += 32) {
    // ---- stage A ----
    if constexpr (AF32) {
      // 16 KB: wave issue = 1 KB = 8 rows of 128 B. lane -> row seg*8+lane/8,
      // phys 16B-unit (lane&7); global col = (unit ^ (row&7)) * 4 f32
      const int r8 = lane >> 3, u = lane & 7;
#pragma unroll
      for (int i = 0; i < 4; ++i) {
        const int seg = i * 4 + wv;
        const int row = seg * 8 + r8;
        const int col = ((u ^ (row & 7)) << 2);
        async16(AsB + seg * 1024, Af + (size_t)(brow + row) * K + k0 + col);
      }
    } else {
      // 8 KB: wave issue = 1 KB = 16 rows of 64 B. lane -> row seg*16+lane/4,
      // phys unit (lane&3); global col = (unit ^ ((row>>1)&3)) * 8 bf16
      const int r4 = lane >> 2, u = lane & 3;
#pragma unroll
      for (int i = 0; i < 2; ++i) {
        const int seg = i * 4 + wv;
        const int row = seg * 16 + r4;
        const int col = ((u ^ ((row >> 1) & 3)) << 3);
        async16(AsB + seg * 1024, Ab + (size_t)(brow + row) * K + k0 + col);
      }
    }
    // ---- stage B (bf16 weights) ----
    {
      const int r4 = lane >> 2, u = lane & 3;
#pragma unroll
      for (int i = 0; i < 2; ++i) {
        const int seg = i * 4 + wv;
        const int row = seg * 16 + r4;
        const int col = ((u ^ ((row >> 1) & 3)) << 3);
        async16(BsB + seg * 1024, Bw + (size_t)(bcol + row) * K + k0 + col);
      }
    }
    __syncthreads();

    // ---- fragments ----
    bf16x8 af[4], bfg[4];
#pragma unroll
    for (int m = 0; m < 4; ++m) {
      const int R = wm + m * 16 + fr;
      if constexpr (AF32) {
        const int x = (R & 7) << 4;
        const f32x4 lo = *(const f32x4*)(AsB + R * 128 + ((fq << 5) ^ x));
        const f32x4 hi = *(const f32x4*)(AsB + R * 128 + (((fq << 5) + 16) ^ x));
        af[m] = cvt8v(lo, hi);
      } else {
        const int ph = (fq << 4) ^ (((R >> 1) & 3) << 4);
        af[m] = *(const bf16x8*)(AsB + R * 64 + ph);
      }
    }
#pragma unroll
    for (int n = 0; n < 4; ++n) {
      const int R = wn + n * 16 + fr;
      const int ph = (fq << 4) ^ (((R >> 1) & 3) << 4);
      bfg[n] = *(const bf16x8*)(BsB + R * 64 + ph);
    }
#pragma unroll
    for (int m = 0; m < 4; ++m)
#pragma unroll
      for (int n = 0; n < 4; ++n)
        acc[m][n] = __builtin_amdgcn_mfma_f32_16x16x32_bf16(af[m], bfg[n], acc[m][n], 0, 0, 0);
    __syncthreads();
  }

  // epilogue: C/D layout col=lane&15, row=(lane>>4)*4+reg
  const int rb = fq * 4;
#pragma unroll
  for (int m = 0; m < 4; ++m)
#pragma unroll
    for (int n = 0; n < 4; ++n)
#pragma unroll
      for (int r = 0; r < 4; ++r) {
        const int row = brow + wm + m * 16 + rb + r;
        const int col = bcol + wn + n * 16 + fr;
        if constexpr (CF32)
          ((float*)Cp)[(size_t)row * N + col] = acc[m][n][r];
        else
          ((bf16_t*)Cp)[(size_t)row * N + col] = (__bf16)acc[m][n][r];
      }
}

// ---------------------------------------------------------------------------
// Fallback GEMM (round-1, fused f32->bf16 cvt, f32 weights) — used only if ws
// is too small for the bf16 weight buffer.
// ---------------------------------------------------------------------------
template<bool A_IS_F32, bool C_IS_F32>
__global__ __launch_bounds__(256)
void gemm_bt(const void* __restrict__ Ap, const float* __restrict__ Bw,
             void* __restrict__ Cp, int M, int N, int K) {
  (void)M;
  __shared__ bf16_t As[128][40];
  __shared__ bf16_t Bs[128][40];
  const int t = (int)threadIdx.x;
  const int lane = t & 63, wv = t >> 6;
  const int wm = (wv >> 1) * 64, wn = (wv & 1) * 64;
  const int brow = (int)blockIdx.y * 128, bcol = (int)blockIdx.x * 128;
  const int fr = lane & 15, fk = (lane >> 4) * 8;

  const f32x4 z = {0.f, 0.f, 0.f, 0.f};
  f32x4 acc[4][4];
#pragma unroll
  for (int m = 0; m < 4; ++m)
#pragma unroll
    for (int n = 0; n < 4; ++n) acc[m][n] = z;

  for (int k0 = 0; k0 < K; k0 += 32) {
    if constexpr (A_IS_F32) {
      const float* A = (const float*)Ap;
      const int tr = t >> 3, tc = (t & 7) * 4;
#pragma unroll
      for (int p = 0; p < 4; ++p) {
        const int r = p * 32 + tr;
        float4 v = *reinterpret_cast<const float4*>(A + (size_t)(brow + r) * K + k0 + tc);
        *reinterpret_cast<bf16x4*>(&As[r][tc]) = cvt4(v);
      }
    } else {
      const bf16_t* A = (const bf16_t*)Ap;
      const int tr = t >> 2, tc = (t & 3) * 8;
#pragma unroll
      for (int p = 0; p < 2; ++p) {
        const int r = p * 64 + tr;
        *reinterpret_cast<int4*>(&As[r][tc]) =
            *reinterpret_cast<const int4*>(A + (size_t)(brow + r) * K + k0 + tc);
      }
    }
    {
      const int tr = t >> 3, tc = (t & 7) * 4;
#pragma unroll
      for (int p = 0; p < 4; ++p) {
        const int r = p * 32 + tr;
        float4 v = *reinterpret_cast<const float4*>(Bw + (size_t)(bcol + r) * K + k0 + tc);
        *reinterpret_cast<bf16x4*>(&Bs[r][tc]) = cvt4(v);
      }
    }
    __syncthreads();
    bf16x8 af[4], bfr[4];
#pragma unroll
    for (int m = 0; m < 4; ++m)
      af[m] = *reinterpret_cast<const bf16x8*>(&As[wm + m * 16 + fr][fk]);
#pragma unroll
    for (int n = 0; n < 4; ++n)
      bfr[n] = *reinterpret_cast<const bf16x8*>(&Bs[wn + n * 16 + fr][fk]);
#pragma unroll
    for (int m = 0; m < 4; ++m)
#pragma unroll
      for (int n = 0; n < 4; ++n)
        acc[m][n] = __builtin_amdgcn_mfma_f32_16x16x32_bf16(af[m], bfr[n], acc[m][n], 0, 0, 0);
    __syncthreads();
  }
  const int rb = (lane >> 4) * 4;
#pragma unroll
  for (int m = 0; m < 4; ++m)
#pragma unroll
    for (int n = 0; n < 4; ++n)
#pragma unroll
      for (int r = 0; r < 4; ++r) {
        const int row = brow + wm + m * 16 + rb + r;
        const int col = bcol + wn + n * 16 + fr;
        if constexpr (C_IS_F32)
          ((float*)Cp)[(size_t)row * N + col] = acc[m][n][r];
        else
          ((bf16_t*)Cp)[(size_t)row * N + col] = (__bf16)acc[m][n][r];
      }
}

// ---------------------------------------------------------------------------
// Fused inverted attention.  Block = (b,h, l-chunk).  Softmax over the N=128
// axis is exact per l-column (fully in-tile) => l-chunks are independent.
// DIRECT: single chunk, divide by R and write bf16 ao.
// !DIRECT: write f32 partial O (cols 0..63) + partial R (col 64), stride 72.
// ---------------------------------------------------------------------------
template<bool DIRECT>
__global__ __launch_bounds__(256)
void attn_inv(const bf16_t* __restrict__ qh, const bf16_t* __restrict__ kh,
              const bf16_t* __restrict__ vh, bf16_t* __restrict__ ao,
              float* __restrict__ part, int lcount) {
  const int bh = (int)blockIdx.x;
  const int b = bh >> 4, h = bh & 15;
  const int l_begin = (int)blockIdx.y * lcount;

  __shared__ bf16_t Qs[128][72];
  __shared__ bf16_t Ks[64][72];
  __shared__ bf16_t Vt[80][72];
  __shared__ bf16_t Ps[128][72];

  const int t = (int)threadIdx.x;
  const int lane = t & 63, w = t >> 6;
  const int fr = lane & 15, fq = lane >> 4;

  const bf16_t* qb = qh + (size_t)(b * CN) * CD + h * CDh;
#pragma unroll
  for (int p = 0; p < 4; ++p) {
    const int j = p * 256 + t;
    const int r = j >> 3, cc = (j & 7) * 8;
    *reinterpret_cast<int4*>(&Qs[r][cc]) =
        *reinterpret_cast<const int4*>(qb + (size_t)r * CD + cc);
  }
#pragma unroll
  for (int p = 0; p < 4; ++p) {
    const int j = p * 256 + t;
    const int r = 64 + (j >> 6), c = j & 63;
    Vt[r][c] = (r == 64) ? (__bf16)1.0f : (__bf16)0.0f;
  }

  const f32x4 z = {0.f, 0.f, 0.f, 0.f};
  f32x4 acc[2][5];
#pragma unroll
  for (int m = 0; m < 2; ++m)
#pragma unroll
    for (int n = 0; n < 5; ++n) acc[m][n] = z;

  for (int l0 = l_begin; l0 < l_begin + lcount; l0 += 64) {
    __syncthreads();
    const bf16_t* kb = kh + (size_t)(b * CL + l0) * CD + h * CDh;
    const bf16_t* vb = vh + (size_t)(b * CL + l0) * CD + h * CDh;
#pragma unroll
    for (int p = 0; p < 2; ++p) {
      const int j = p * 256 + t;
      const int r = j >> 3, cc = (j & 7) * 8;
      *reinterpret_cast<int4*>(&Ks[r][cc]) =
          *reinterpret_cast<const int4*>(kb + (size_t)r * CD + cc);
      int4 vv = *reinterpret_cast<const int4*>(vb + (size_t)r * CD + cc);
      const bf16_t* hp = reinterpret_cast<const bf16_t*>(&vv);
#pragma unroll
      for (int i = 0; i < 8; ++i) Vt[cc + i][r] = hp[i];
    }
    __syncthreads();

    f32x4 s[8];
#pragma unroll
    for (int m = 0; m < 8; ++m) s[m] = z;
#pragma unroll
    for (int ks = 0; ks < 2; ++ks) {
      bf16x8 bk = *reinterpret_cast<const bf16x8*>(&Ks[w * 16 + fr][ks * 32 + fq * 8]);
#pragma unroll
      for (int m = 0; m < 8; ++m) {
        bf16x8 aq = *reinterpret_cast<const bf16x8*>(&Qs[m * 16 + fr][ks * 32 + fq * 8]);
        s[m] = __builtin_amdgcn_mfma_f32_16x16x32_bf16(aq, bk, s[m], 0, 0, 0);
      }
    }

    float p[8][4];
    float mx = -3.0e38f;
#pragma unroll
    for (int m = 0; m < 8; ++m)
#pragma unroll
      for (int r = 0; r < 4; ++r) {
        const float x = s[m][r] * 0.03125f;
        p[m][r] = x;
        mx = fmaxf(mx, x);
      }
    mx = fmaxf(mx, __shfl_xor(mx, 16));
    mx = fmaxf(mx, __shfl_xor(mx, 32));
    float sum = 0.f;
#pragma unroll
    for (int m = 0; m < 8; ++m)
#pragma unroll
      for (int r = 0; r < 4; ++r) {
        const float e = __expf(p[m][r] - mx);
        p[m][r] = e;
        sum += e;
      }
    sum += __shfl_xor(sum, 16);
    sum += __shfl_xor(sum, 32);
    const float inv = 1.0f / sum;
    const int pcol = w * 16 + fr;
#pragma unroll
    for (int m = 0; m < 8; ++m)
#pragma unroll
      for (int r = 0; r < 4; ++r)
        Ps[m * 16 + fq * 4 + r][pcol] = (__bf16)(p[m][r] * inv);
    __syncthreads();

#pragma unroll
    for (int ks = 0; ks < 2; ++ks) {
      bf16x8 pa[2];
#pragma unroll
      for (int m = 0; m < 2; ++m)
        pa[m] = *reinterpret_cast<const bf16x8*>(&Ps[w * 32 + m * 16 + fr][ks * 32 + fq * 8]);
#pragma unroll
      for (int n = 0; n < 5; ++n) {
        bf16x8 bv = *reinterpret_cast<const bf16x8*>(&Vt[n * 16 + fr][ks * 32 + fq * 8]);
#pragma unroll
        for (int m = 0; m < 2; ++m)
          acc[m][n] = __builtin_amdgcn_mfma_f32_16x16x32_bf16(pa[m], bv, acc[m][n], 0, 0, 0);
      }
    }
  }

  if constexpr (DIRECT) {
    bf16_t* ob = ao + (size_t)(b * CN) * CD + h * CDh;
#pragma unroll
    for (int m = 0; m < 2; ++m)
#pragma unroll
      for (int r = 0; r < 4; ++r) {
        const float R = __shfl(acc[m][4][r], lane & 48);
        const float invr = 1.0f / R;
        const int row = w * 32 + m * 16 + fq * 4 + r;
#pragma unroll
        for (int n = 0; n < 4; ++n) {
          const int col = n * 16 + fr;
          ob[(size_t)row * CD + col] = (__bf16)(acc[m][n][r] * invr);
        }
      }
  } else {
    float* pb = part + ((size_t)blockIdx.y * (CB * CH) + bh) * (size_t)(CN * 72);
#pragma unroll
    for (int m = 0; m < 2; ++m)
#pragma unroll
      for (int r = 0; r < 4; ++r) {
        const int row = w * 32 + m * 16 + fq * 4 + r;
#pragma unroll
        for (int n = 0; n < 4; ++n)
          pb[(size_t)row * 72 + n * 16 + fr] = acc[m][n][r];
        if (fr == 0) pb[(size_t)row * 72 + 64] = acc[m][4][r];
      }
  }
}

// reduce partials over splits, divide by R, write bf16 ao[b,n, h*64+c]
__global__ __launch_bounds__(256)
void attn_reduce(const float* __restrict__ part, bf16_t* __restrict__ ao, int nsplit) {
  const int idx = (int)blockIdx.x * 256 + (int)threadIdx.x;
  const int c = idx & 63;
  const int n = (idx >> 6) & 127;
  const int bh = idx >> 13;
  const float* p = part + (size_t)bh * (CN * 72) + (size_t)n * 72;
  const size_t sstr = (size_t)(CB * CH) * (CN * 72);
  float o = 0.f, r = 0.f;
  for (int s = 0; s < nsplit; ++s) {
    o += p[(size_t)s * sstr + c];
    r += p[(size_t)s * sstr + 64];
  }
  const int b = bh >> 4, h = bh & 15;
  ao[((size_t)(b * CN + n)) * CD + h * CDh + c] = (__bf16)(o / r);
}

extern "C" void kernel_launch(void* const* d_in, const int* in_sizes, int n_in,
                              void* d_out, int out_size, void* d_ws, size_t ws_size,
                              hipStream_t stream) {
  (void)in_sizes; (void)n_in; (void)out_size;
  const float* q  = (const float*)d_in[0];
  const float* k  = (const float*)d_in[1];
  const float* v  = (const float*)d_in[2];
  const float* Wq = (const float*)d_in[3];
  const float* Wk = (const float*)d_in[4];
  const float* Wv = (const float*)d_in[5];
  const float* Wo = (const float*)d_in[6];
  float* out = (float*)d_out;

  const size_t MiB = (size_t)1 << 20;
  const size_t QH_OFF = 0;
  const size_t KH_OFF = 2 * MiB;
  const size_t VH_OFF = KH_OFF + 64 * MiB;
  const size_t AO_OFF = VH_OFF + 64 * MiB;
  const size_t FIXED  = AO_OFF + 2 * MiB;  // 132 MiB (known to fit from round 1)
  if (ws_size < FIXED) return;

  char* ws = (char*)d_ws;
  bf16_t* qh = (bf16_t*)(ws + QH_OFF);
  bf16_t* kh = (bf16_t*)(ws + KH_OFF);
  bf16_t* vh = (bf16_t*)(ws + VH_OFF);
  bf16_t* ao = (bf16_t*)(ws + AO_OFF);

  const size_t extra = ws_size - FIXED;
  const bool newgemm = extra >= 2 * MiB;              // room for bf16 weight buf
  bf16_t* wbuf = (bf16_t*)(ws + FIXED);
  const size_t PB = (size_t)CB * CH * CN * 72 * 4;    // 4,718,592 B per split
  const size_t pav = newgemm ? (extra - 2 * MiB) : 0;
  int nsplit = 8;
  while (nsplit > 1 && (size_t)nsplit * PB > pav) nsplit >>= 1;
  float* part = (float*)(ws + FIXED + 2 * MiB);

  const int M_q = CB * CN;    // 1024
  const int M_kv = CB * CL;   // 32768
  const int W4 = CD * CD / 4; // 262144 float4s per weight

  if (newgemm) {
    cvt_f32_bf16<<<W4 / 256, 256, 0, stream>>>(Wq, wbuf, W4);
    gemm_dma<true, false><<<(M_q / 128) * 8, 256, 0, stream>>>(q, wbuf, qh, M_q / 128, CD, CD);
    cvt_f32_bf16<<<W4 / 256, 256, 0, stream>>>(Wk, wbuf, W4);
    gemm_dma<true, false><<<(M_kv / 128) * 8, 256, 0, stream>>>(k, wbuf, kh, M_kv / 128, CD, CD);
    cvt_f32_bf16<<<W4 / 256, 256, 0, stream>>>(Wv, wbuf, W4);
    gemm_dma<true, false><<<(M_kv / 128) * 8, 256, 0, stream>>>(v, wbuf, vh, M_kv / 128, CD, CD);
  } else {
    gemm_bt<true, false><<<dim3(CD / 128, M_q / 128),  256, 0, stream>>>(q, Wq, qh, M_q,  CD, CD);
    gemm_bt<true, false><<<dim3(CD / 128, M_kv / 128), 256, 0, stream>>>(k, Wk, kh, M_kv, CD, CD);
    gemm_bt<true, false><<<dim3(CD / 128, M_kv / 128), 256, 0, stream>>>(v, Wv, vh, M_kv, CD, CD);
  }

  if (nsplit > 1) {
    attn_inv<false><<<dim3(CB * CH, nsplit), 256, 0, stream>>>(qh, kh, vh, ao, part, CL / nsplit);
    attn_reduce<<<(CB * CH * CN * 64) / 256, 256, 0, stream>>>(part, ao, nsplit);
  } else {
    attn_inv<true><<<dim3(CB * CH, 1), 256, 0, stream>>>(qh, kh, vh, ao, nullptr, CL);
  }

  if (newgemm) {
    cvt_f32_bf16<<<W4 / 256, 256, 0, stream>>>(Wo, wbuf, W4);
    gemm_dma<false, true><<<(M_q / 128) * 8, 256, 0, stream>>>(ao, wbuf, out, M_q / 128, CD, CD);
  } else {
    gemm_bt<false, true><<<dim3(CD / 128, M_q / 128), 256, 0, stream>>>(ao, Wo, out, M_q, CD, CD);
  }
}

// Round 3
// 424.406 us; speedup vs baseline: 1.3914x; 1.0922x over previous
//
#include <hip/hip_runtime.h>
#include <stdint.h>

typedef __bf16 bf16_t;
typedef __bf16 bf16x4 __attribute__((ext_vector_type(4)));
typedef __bf16 bf16x8 __attribute__((ext_vector_type(8)));
typedef float f32x4 __attribute__((ext_vector_type(4)));
typedef unsigned int u32;

// Problem constants (B, N, L, D, H) = (8, 128, 4096, 1024, 16)
constexpr int CB = 8, CN = 128, CL = 4096, CD = 1024, CH = 16, CDh = 64;

__device__ __forceinline__ bf16x4 cvt4(float4 v) {
  bf16x4 r;
  r[0] = (__bf16)v.x; r[1] = (__bf16)v.y; r[2] = (__bf16)v.z; r[3] = (__bf16)v.w;
  return r;
}
__device__ __forceinline__ bf16x8 cvt8v(f32x4 lo, f32x4 hi) {
  bf16x8 r;
#pragma unroll
  for (int i = 0; i < 4; ++i) { r[i] = (__bf16)lo[i]; r[i + 4] = (__bf16)hi[i]; }
  return r;
}

// async global->LDS, 16 B per lane. LDS dest is wave-uniform base + lane*16.
__device__ __forceinline__ void async16(void* lds, const void* g) {
  __builtin_amdgcn_global_load_lds(
      (const __attribute__((address_space(1))) u32*)g,
      (__attribute__((address_space(3))) u32*)lds, 16, 0, 0);
}

// f32 -> bf16 elementwise (for weights), n4 = elems/4
__global__ __launch_bounds__(256) void cvt_f32_bf16(const float* __restrict__ in,
                                                    bf16_t* __restrict__ outp, int n4) {
  int i = (int)blockIdx.x * 256 + (int)threadIdx.x;
  if (i < n4) {
    float4 v = reinterpret_cast<const float4*>(in)[i];
    reinterpret_cast<bf16x4*>(outp)[i] = cvt4(v);
  }
}

// ---------------------------------------------------------------------------
// DMA-staged GEMM: C[M,N] = A[M,K] @ Wb[N,K]^T.  A f32 (AF32) or bf16.
// Wb always bf16.  128x128 tile, BK=32, 4 waves, global_load_lds width-16,
// source-side XOR swizzle (linear DMA dest + pre-swizzled global src + swizzled
// ds_read).
// XCD mapping (round-3 fix): dispatch round-robins bid%8 across XCDs, so XCD x
// gets j = bid>>3 = 0..cpx-1 in order. Give each XCD a DISTINCT M-stripe
// (mblocks/8 blocks) and iterate the 8 N-blocks INNERMOST: consecutive blocks
// on one XCD share the same 512 KB A panel (L2-resident) and the 2 MB W
// (L2-resident) -> A is fetched from HBM once total, not once per XCD.
// Requires mblocks % 8 == 0 and N == 1024 (8 n-blocks).
// ---------------------------------------------------------------------------
template<bool AF32, bool CF32>
__global__ __launch_bounds__(256)
void gemm_dma(const void* __restrict__ Ap, const bf16_t* __restrict__ Bw,
              void* __restrict__ Cp, int mblocks, int N, int K) {
  __shared__ __attribute__((aligned(16))) char AsB[AF32 ? 16384 : 8192];
  __shared__ __attribute__((aligned(16))) char BsB[8192];

  const int t = (int)threadIdx.x;
  const int lane = t & 63, wv = t >> 6;
  const int bid = (int)blockIdx.x;
  const int x = bid & 7;            // XCD id (dispatch round-robin)
  const int j = bid >> 3;           // sequence index within XCD
  const int S = mblocks >> 3;       // M-blocks per XCD stripe
  const int mb = x * S + (j >> 3);  // distinct M-stripe per XCD
  const int nb = j & 7;             // N-block innermost -> A panel L2-resident
  const int brow = mb * 128;
  const int bcol = nb * 128;
  const int wm = (wv >> 1) * 64, wn = (wv & 1) * 64;
  const int fr = lane & 15, fq = lane >> 4;

  const float*  Af = (const float*)Ap;
  const bf16_t* Ab = (const bf16_t*)Ap;

  const f32x4 z = {0.f, 0.f, 0.f, 0.f};
  f32x4 acc[4][4];
#pragma unroll
  for (int m = 0; m < 4; ++m)
#pragma unroll
    for (int n = 0; n < 4; ++n) acc[m][n] = z;

  for (int k0 = 0; k0 < K; k0 += 32) {
    // ---- stage A ----
    if constexpr (AF32) {
      // 16 KB: wave issue = 1 KB = 8 rows of 128 B. lane -> row seg*8+lane/8,
      // phys 16B-unit (lane&7); global col = (unit ^ (row&7)) * 4 f32
      const int r8 = lane >> 3, u = lane & 7;
#pragma unroll
      for (int i = 0; i < 4; ++i) {
        const int seg = i * 4 + wv;
        const int row = seg * 8 + r8;
        const int col = ((u ^ (row & 7)) << 2);
        async16(AsB + seg * 1024, Af + (size_t)(brow + row) * K + k0 + col);
      }
    } else {
      // 8 KB: wave issue = 1 KB = 16 rows of 64 B. lane -> row seg*16+lane/4,
      // phys unit (lane&3); global col = (unit ^ ((row>>1)&3)) * 8 bf16
      const int r4 = lane >> 2, u = lane & 3;
#pragma unroll
      for (int i = 0; i < 2; ++i) {
        const int seg = i * 4 + wv;
        const int row = seg * 16 + r4;
        const int col = ((u ^ ((row >> 1) & 3)) << 3);
        async16(AsB + seg * 1024, Ab + (size_t)(brow + row) * K + k0 + col);
      }
    }
    // ---- stage B (bf16 weights) ----
    {
      const int r4 = lane >> 2, u = lane & 3;
#pragma unroll
      for (int i = 0; i < 2; ++i) {
        const int seg = i * 4 + wv;
        const int row = seg * 16 + r4;
        const int col = ((u ^ ((row >> 1) & 3)) << 3);
        async16(BsB + seg * 1024, Bw + (size_t)(bcol + row) * K + k0 + col);
      }
    }
    __syncthreads();

    // ---- fragments ----
    bf16x8 af[4], bfg[4];
#pragma unroll
    for (int m = 0; m < 4; ++m) {
      const int R = wm + m * 16 + fr;
      if constexpr (AF32) {
        const int xx = (R & 7) << 4;
        const f32x4 lo = *(const f32x4*)(AsB + R * 128 + ((fq << 5) ^ xx));
        const f32x4 hi = *(const f32x4*)(AsB + R * 128 + (((fq << 5) + 16) ^ xx));
        af[m] = cvt8v(lo, hi);
      } else {
        const int ph = (fq << 4) ^ (((R >> 1) & 3) << 4);
        af[m] = *(const bf16x8*)(AsB + R * 64 + ph);
      }
    }
#pragma unroll
    for (int n = 0; n < 4; ++n) {
      const int R = wn + n * 16 + fr;
      const int ph = (fq << 4) ^ (((R >> 1) & 3) << 4);
      bfg[n] = *(const bf16x8*)(BsB + R * 64 + ph);
    }
#pragma unroll
    for (int m = 0; m < 4; ++m)
#pragma unroll
      for (int n = 0; n < 4; ++n)
        acc[m][n] = __builtin_amdgcn_mfma_f32_16x16x32_bf16(af[m], bfg[n], acc[m][n], 0, 0, 0);
    __syncthreads();
  }

  // epilogue: C/D layout col=lane&15, row=(lane>>4)*4+reg
  const int rb = fq * 4;
#pragma unroll
  for (int m = 0; m < 4; ++m)
#pragma unroll
    for (int n = 0; n < 4; ++n)
#pragma unroll
      for (int r = 0; r < 4; ++r) {
        const int row = brow + wm + m * 16 + rb + r;
        const int col = bcol + wn + n * 16 + fr;
        if constexpr (CF32)
          ((float*)Cp)[(size_t)row * N + col] = acc[m][n][r];
        else
          ((bf16_t*)Cp)[(size_t)row * N + col] = (__bf16)acc[m][n][r];
      }
}

// ---------------------------------------------------------------------------
// Fallback GEMM (round-1, fused f32->bf16 cvt, f32 weights) — used only if ws
// is too small for the bf16 weight buffer.
// ---------------------------------------------------------------------------
template<bool A_IS_F32, bool C_IS_F32>
__global__ __launch_bounds__(256)
void gemm_bt(const void* __restrict__ Ap, const float* __restrict__ Bw,
             void* __restrict__ Cp, int M, int N, int K) {
  (void)M;
  __shared__ bf16_t As[128][40];
  __shared__ bf16_t Bs[128][40];
  const int t = (int)threadIdx.x;
  const int lane = t & 63, wv = t >> 6;
  const int wm = (wv >> 1) * 64, wn = (wv & 1) * 64;
  const int brow = (int)blockIdx.y * 128, bcol = (int)blockIdx.x * 128;
  const int fr = lane & 15, fk = (lane >> 4) * 8;

  const f32x4 z = {0.f, 0.f, 0.f, 0.f};
  f32x4 acc[4][4];
#pragma unroll
  for (int m = 0; m < 4; ++m)
#pragma unroll
    for (int n = 0; n < 4; ++n) acc[m][n] = z;

  for (int k0 = 0; k0 < K; k0 += 32) {
    if constexpr (A_IS_F32) {
      const float* A = (const float*)Ap;
      const int tr = t >> 3, tc = (t & 7) * 4;
#pragma unroll
      for (int p = 0; p < 4; ++p) {
        const int r = p * 32 + tr;
        float4 v = *reinterpret_cast<const float4*>(A + (size_t)(brow + r) * K + k0 + tc);
        *reinterpret_cast<bf16x4*>(&As[r][tc]) = cvt4(v);
      }
    } else {
      const bf16_t* A = (const bf16_t*)Ap;
      const int tr = t >> 2, tc = (t & 3) * 8;
#pragma unroll
      for (int p = 0; p < 2; ++p) {
        const int r = p * 64 + tr;
        *reinterpret_cast<int4*>(&As[r][tc]) =
            *reinterpret_cast<const int4*>(A + (size_t)(brow + r) * K + k0 + tc);
      }
    }
    {
      const int tr = t >> 3, tc = (t & 7) * 4;
#pragma unroll
      for (int p = 0; p < 4; ++p) {
        const int r = p * 32 + tr;
        float4 v = *reinterpret_cast<const float4*>(Bw + (size_t)(bcol + r) * K + k0 + tc);
        *reinterpret_cast<bf16x4*>(&Bs[r][tc]) = cvt4(v);
      }
    }
    __syncthreads();
    bf16x8 af[4], bfr[4];
#pragma unroll
    for (int m = 0; m < 4; ++m)
      af[m] = *reinterpret_cast<const bf16x8*>(&As[wm + m * 16 + fr][fk]);
#pragma unroll
    for (int n = 0; n < 4; ++n)
      bfr[n] = *reinterpret_cast<const bf16x8*>(&Bs[wn + n * 16 + fr][fk]);
#pragma unroll
    for (int m = 0; m < 4; ++m)
#pragma unroll
      for (int n = 0; n < 4; ++n)
        acc[m][n] = __builtin_amdgcn_mfma_f32_16x16x32_bf16(af[m], bfr[n], acc[m][n], 0, 0, 0);
    __syncthreads();
  }
  const int rb = (lane >> 4) * 4;
#pragma unroll
  for (int m = 0; m < 4; ++m)
#pragma unroll
    for (int n = 0; n < 4; ++n)
#pragma unroll
      for (int r = 0; r < 4; ++r) {
        const int row = brow + wm + m * 16 + rb + r;
        const int col = bcol + wn + n * 16 + fr;
        if constexpr (C_IS_F32)
          ((float*)Cp)[(size_t)row * N + col] = acc[m][n][r];
        else
          ((bf16_t*)Cp)[(size_t)row * N + col] = (__bf16)acc[m][n][r];
      }
}

// ---------------------------------------------------------------------------
// Fused inverted attention.  Block = (b,h, l-chunk).  Softmax over the N=128
// axis is exact per l-column (fully in-tile) => l-chunks are independent.
// DIRECT: single chunk, divide by R and write bf16 ao.
// !DIRECT: write f32 partial O (cols 0..63) + partial R (col 64), stride 72.
// ---------------------------------------------------------------------------
template<bool DIRECT>
__global__ __launch_bounds__(256)
void attn_inv(const bf16_t* __restrict__ qh, const bf16_t* __restrict__ kh,
              const bf16_t* __restrict__ vh, bf16_t* __restrict__ ao,
              float* __restrict__ part, int lcount) {
  const int bh = (int)blockIdx.x;
  const int b = bh >> 4, h = bh & 15;
  const int l_begin = (int)blockIdx.y * lcount;

  __shared__ bf16_t Qs[128][72];
  __shared__ bf16_t Ks[64][72];
  __shared__ bf16_t Vt[80][72];
  __shared__ bf16_t Ps[128][72];

  const int t = (int)threadIdx.x;
  const int lane = t & 63, w = t >> 6;
  const int fr = lane & 15, fq = lane >> 4;

  const bf16_t* qb = qh + (size_t)(b * CN) * CD + h * CDh;
#pragma unroll
  for (int p = 0; p < 4; ++p) {
    const int j = p * 256 + t;
    const int r = j >> 3, cc = (j & 7) * 8;
    *reinterpret_cast<int4*>(&Qs[r][cc]) =
        *reinterpret_cast<const int4*>(qb + (size_t)r * CD + cc);
  }
#pragma unroll
  for (int p = 0; p < 4; ++p) {
    const int j = p * 256 + t;
    const int r = 64 + (j >> 6), c = j & 63;
    Vt[r][c] = (r == 64) ? (__bf16)1.0f : (__bf16)0.0f;
  }

  const f32x4 z = {0.f, 0.f, 0.f, 0.f};
  f32x4 acc[2][5];
#pragma unroll
  for (int m = 0; m < 2; ++m)
#pragma unroll
    for (int n = 0; n < 5; ++n) acc[m][n] = z;

  for (int l0 = l_begin; l0 < l_begin + lcount; l0 += 64) {
    __syncthreads();
    const bf16_t* kb = kh + (size_t)(b * CL + l0) * CD + h * CDh;
    const bf16_t* vb = vh + (size_t)(b * CL + l0) * CD + h * CDh;
#pragma unroll
    for (int p = 0; p < 2; ++p) {
      const int j = p * 256 + t;
      const int r = j >> 3, cc = (j & 7) * 8;
      *reinterpret_cast<int4*>(&Ks[r][cc]) =
          *reinterpret_cast<const int4*>(kb + (size_t)r * CD + cc);
      int4 vv = *reinterpret_cast<const int4*>(vb + (size_t)r * CD + cc);
      const bf16_t* hp = reinterpret_cast<const bf16_t*>(&vv);
#pragma unroll
      for (int i = 0; i < 8; ++i) Vt[cc + i][r] = hp[i];
    }
    __syncthreads();

    f32x4 s[8];
#pragma unroll
    for (int m = 0; m < 8; ++m) s[m] = z;
#pragma unroll
    for (int ks = 0; ks < 2; ++ks) {
      bf16x8 bk = *reinterpret_cast<const bf16x8*>(&Ks[w * 16 + fr][ks * 32 + fq * 8]);
#pragma unroll
      for (int m = 0; m < 8; ++m) {
        bf16x8 aq = *reinterpret_cast<const bf16x8*>(&Qs[m * 16 + fr][ks * 32 + fq * 8]);
        s[m] = __builtin_amdgcn_mfma_f32_16x16x32_bf16(aq, bk, s[m], 0, 0, 0);
      }
    }

    float p[8][4];
    float mx = -3.0e38f;
#pragma unroll
    for (int m = 0; m < 8; ++m)
#pragma unroll
      for (int r = 0; r < 4; ++r) {
        const float x = s[m][r] * 0.03125f;
        p[m][r] = x;
        mx = fmaxf(mx, x);
      }
    mx = fmaxf(mx, __shfl_xor(mx, 16));
    mx = fmaxf(mx, __shfl_xor(mx, 32));
    float sum = 0.f;
#pragma unroll
    for (int m = 0; m < 8; ++m)
#pragma unroll
      for (int r = 0; r < 4; ++r) {
        const float e = __expf(p[m][r] - mx);
        p[m][r] = e;
        sum += e;
      }
    sum += __shfl_xor(sum, 16);
    sum += __shfl_xor(sum, 32);
    const float inv = 1.0f / sum;
    const int pcol = w * 16 + fr;
#pragma unroll
    for (int m = 0; m < 8; ++m)
#pragma unroll
      for (int r = 0; r < 4; ++r)
        Ps[m * 16 + fq * 4 + r][pcol] = (__bf16)(p[m][r] * inv);
    __syncthreads();

#pragma unroll
    for (int ks = 0; ks < 2; ++ks) {
      bf16x8 pa[2];
#pragma unroll
      for (int m = 0; m < 2; ++m)
        pa[m] = *reinterpret_cast<const bf16x8*>(&Ps[w * 32 + m * 16 + fr][ks * 32 + fq * 8]);
#pragma unroll
      for (int n = 0; n < 5; ++n) {
        bf16x8 bv = *reinterpret_cast<const bf16x8*>(&Vt[n * 16 + fr][ks * 32 + fq * 8]);
#pragma unroll
        for (int m = 0; m < 2; ++m)
          acc[m][n] = __builtin_amdgcn_mfma_f32_16x16x32_bf16(pa[m], bv, acc[m][n], 0, 0, 0);
      }
    }
  }

  if constexpr (DIRECT) {
    bf16_t* ob = ao + (size_t)(b * CN) * CD + h * CDh;
#pragma unroll
    for (int m = 0; m < 2; ++m)
#pragma unroll
      for (int r = 0; r < 4; ++r) {
        const float R = __shfl(acc[m][4][r], lane & 48);
        const float invr = 1.0f / R;
        const int row = w * 32 + m * 16 + fq * 4 + r;
#pragma unroll
        for (int n = 0; n < 4; ++n) {
          const int col = n * 16 + fr;
          ob[(size_t)row * CD + col] = (__bf16)(acc[m][n][r] * invr);
        }
      }
  } else {
    float* pb = part + ((size_t)blockIdx.y * (CB * CH) + bh) * (size_t)(CN * 72);
#pragma unroll
    for (int m = 0; m < 2; ++m)
#pragma unroll
      for (int r = 0; r < 4; ++r) {
        const int row = w * 32 + m * 16 + fq * 4 + r;
#pragma unroll
        for (int n = 0; n < 4; ++n)
          pb[(size_t)row * 72 + n * 16 + fr] = acc[m][n][r];
        if (fr == 0) pb[(size_t)row * 72 + 64] = acc[m][4][r];
      }
  }
}

// reduce partials over splits, divide by R, write bf16 ao[b,n, h*64+c]
__global__ __launch_bounds__(256)
void attn_reduce(const float* __restrict__ part, bf16_t* __restrict__ ao, int nsplit) {
  const int idx = (int)blockIdx.x * 256 + (int)threadIdx.x;
  const int c = idx & 63;
  const int n = (idx >> 6) & 127;
  const int bh = idx >> 13;
  const float* p = part + (size_t)bh * (CN * 72) + (size_t)n * 72;
  const size_t sstr = (size_t)(CB * CH) * (CN * 72);
  float o = 0.f, r = 0.f;
  for (int s = 0; s < nsplit; ++s) {
    o += p[(size_t)s * sstr + c];
    r += p[(size_t)s * sstr + 64];
  }
  const int b = bh >> 4, h = bh & 15;
  ao[((size_t)(b * CN + n)) * CD + h * CDh + c] = (__bf16)(o / r);
}

extern "C" void kernel_launch(void* const* d_in, const int* in_sizes, int n_in,
                              void* d_out, int out_size, void* d_ws, size_t ws_size,
                              hipStream_t stream) {
  (void)in_sizes; (void)n_in; (void)out_size;
  const float* q  = (const float*)d_in[0];
  const float* k  = (const float*)d_in[1];
  const float* v  = (const float*)d_in[2];
  const float* Wq = (const float*)d_in[3];
  const float* Wk = (const float*)d_in[4];
  const float* Wv = (const float*)d_in[5];
  const float* Wo = (const float*)d_in[6];
  float* out = (float*)d_out;

  const size_t MiB = (size_t)1 << 20;
  const size_t QH_OFF = 0;
  const size_t KH_OFF = 2 * MiB;
  const size_t VH_OFF = KH_OFF + 64 * MiB;
  const size_t AO_OFF = VH_OFF + 64 * MiB;
  const size_t FIXED  = AO_OFF + 2 * MiB;  // 132 MiB (known to fit)
  if (ws_size < FIXED) return;

  char* ws = (char*)d_ws;
  bf16_t* qh = (bf16_t*)(ws + QH_OFF);
  bf16_t* kh = (bf16_t*)(ws + KH_OFF);
  bf16_t* vh = (bf16_t*)(ws + VH_OFF);
  bf16_t* ao = (bf16_t*)(ws + AO_OFF);

  const size_t extra = ws_size - FIXED;
  const bool newgemm = extra >= 2 * MiB;              // room for bf16 weight buf
  bf16_t* wbuf = (bf16_t*)(ws + FIXED);
  const size_t PB = (size_t)CB * CH * CN * 72 * 4;    // 4,718,592 B per split
  const size_t pav = newgemm ? (extra - 2 * MiB) : 0;
  int nsplit = 8;
  while (nsplit > 1 && (size_t)nsplit * PB > pav) nsplit >>= 1;
  float* part = (float*)(ws + FIXED + 2 * MiB);

  const int M_q = CB * CN;    // 1024
  const int M_kv = CB * CL;   // 32768
  const int W4 = CD * CD / 4; // 262144 float4s per weight

  if (newgemm) {
    cvt_f32_bf16<<<W4 / 256, 256, 0, stream>>>(Wq, wbuf, W4);
    gemm_dma<true, false><<<(M_q / 128) * 8, 256, 0, stream>>>(q, wbuf, qh, M_q / 128, CD, CD);
    cvt_f32_bf16<<<W4 / 256, 256, 0, stream>>>(Wk, wbuf, W4);
    gemm_dma<true, false><<<(M_kv / 128) * 8, 256, 0, stream>>>(k, wbuf, kh, M_kv / 128, CD, CD);
    cvt_f32_bf16<<<W4 / 256, 256, 0, stream>>>(Wv, wbuf, W4);
    gemm_dma<true, false><<<(M_kv / 128) * 8, 256, 0, stream>>>(v, wbuf, vh, M_kv / 128, CD, CD);
  } else {
    gemm_bt<true, false><<<dim3(CD / 128, M_q / 128),  256, 0, stream>>>(q, Wq, qh, M_q,  CD, CD);
    gemm_bt<true, false><<<dim3(CD / 128, M_kv / 128), 256, 0, stream>>>(k, Wk, kh, M_kv, CD, CD);
    gemm_bt<true, false><<<dim3(CD / 128, M_kv / 128), 256, 0, stream>>>(v, Wv, vh, M_kv, CD, CD);
  }

  if (nsplit > 1) {
    attn_inv<false><<<dim3(CB * CH, nsplit), 256, 0, stream>>>(qh, kh, vh, ao, part, CL / nsplit);
    attn_reduce<<<(CB * CH * CN * 64) / 256, 256, 0, stream>>>(part, ao, nsplit);
  } else {
    attn_inv<true><<<dim3(CB * CH, 1), 256, 0, stream>>>(qh, kh, vh, ao, nullptr, CL);
  }

  if (newgemm) {
    cvt_f32_bf16<<<W4 / 256, 256, 0, stream>>>(Wo, wbuf, W4);
    gemm_dma<false, true><<<(M_q / 128) * 8, 256, 0, stream>>>(ao, wbuf, out, M_q / 128, CD, CD);
  } else {
    gemm_bt<false, true><<<dim3(CD / 128, M_q / 128), 256, 0, stream>>>(ao, Wo, out, M_q, CD, CD);
  }
}

// Round 4
// 413.645 us; speedup vs baseline: 1.4276x; 1.0260x over previous
//
#include <hip/hip_runtime.h>
#include <stdint.h>

typedef __bf16 bf16_t;
typedef __bf16 bf16x4 __attribute__((ext_vector_type(4)));
typedef __bf16 bf16x8 __attribute__((ext_vector_type(8)));
typedef float f32x4 __attribute__((ext_vector_type(4)));
typedef unsigned int u32;

// Problem constants (B, N, L, D, H) = (8, 128, 4096, 1024, 16)
constexpr int CB = 8, CN = 128, CL = 4096, CD = 1024, CH = 16, CDh = 64;

__device__ __forceinline__ bf16x4 cvt4(float4 v) {
  bf16x4 r;
  r[0] = (__bf16)v.x; r[1] = (__bf16)v.y; r[2] = (__bf16)v.z; r[3] = (__bf16)v.w;
  return r;
}
__device__ __forceinline__ bf16x8 cvt8v(f32x4 lo, f32x4 hi) {
  bf16x8 r;
#pragma unroll
  for (int i = 0; i < 4; ++i) { r[i] = (__bf16)lo[i]; r[i + 4] = (__bf16)hi[i]; }
  return r;
}

// async global->LDS, 16 B per lane. LDS dest is wave-uniform base + lane*16.
__device__ __forceinline__ void async16(void* lds, const void* g) {
  __builtin_amdgcn_global_load_lds(
      (const __attribute__((address_space(1))) u32*)g,
      (__attribute__((address_space(3))) u32*)lds, 16, 0, 0);
}

// f32 -> bf16 elementwise (for weights), n4 = elems/4
__global__ __launch_bounds__(256) void cvt_f32_bf16(const float* __restrict__ in,
                                                    bf16_t* __restrict__ outp, int n4) {
  int i = (int)blockIdx.x * 256 + (int)threadIdx.x;
  if (i < n4) {
    float4 v = reinterpret_cast<const float4*>(in)[i];
    reinterpret_cast<bf16x4*>(outp)[i] = cvt4(v);
  }
}

// ---------------------------------------------------------------------------
// DMA-staged GEMM, 2-phase double-buffered K-loop (round 4).
// C[M,N] = A[M,K] @ Wb[N,K]^T.  A f32 (AF32) or bf16; Wb always bf16.
// 128x128 tile, BK=32, 4 waves, global_load_lds width-16, source-side XOR
// swizzle (linear DMA dest + pre-swizzled global src + swizzled ds_read).
// K-loop: issue next tile's global_load_lds into buf^1 BEFORE computing
// buf[cur]; single __syncthreads per step (drains vmcnt+lgkmcnt). Load
// latency (~900cy HBM-miss) overlaps current tile's MFMA+cvt instead of
// being serially exposed at a stage->barrier->compute boundary.
// XCD mapping: bid%8 = XCD; each XCD owns a distinct M-stripe, 8 N-blocks
// innermost (A panel + W L2-locality best-effort).
// ---------------------------------------------------------------------------
template<bool AF32, bool CF32>
__global__ __launch_bounds__(256)
void gemm_dma(const void* __restrict__ Ap, const bf16_t* __restrict__ Bw,
              void* __restrict__ Cp, int mblocks, int N, int K) {
  constexpr int ASZ = AF32 ? 16384 : 8192;
  __shared__ __attribute__((aligned(16))) char AsB[2][ASZ];
  __shared__ __attribute__((aligned(16))) char BsB[2][8192];

  const int t = (int)threadIdx.x;
  const int lane = t & 63, wv = t >> 6;
  const int bid = (int)blockIdx.x;
  const int x = bid & 7;            // XCD id (dispatch round-robin)
  const int j = bid >> 3;           // sequence index within XCD
  const int S = mblocks >> 3;       // M-blocks per XCD stripe
  const int mb = x * S + (j >> 3);  // distinct M-stripe per XCD
  const int nb = j & 7;             // N-block innermost
  const int brow = mb * 128;
  const int bcol = nb * 128;
  const int wm = (wv >> 1) * 64, wn = (wv & 1) * 64;
  const int fr = lane & 15, fq = lane >> 4;

  const float*  Af = (const float*)Ap;
  const bf16_t* Ab = (const bf16_t*)Ap;

  auto stageA = [&](char* dst, int k0) {
    if constexpr (AF32) {
      // 16 KB: wave issue = 1 KB = 8 rows of 128 B.
      const int r8 = lane >> 3, u = lane & 7;
#pragma unroll
      for (int i = 0; i < 4; ++i) {
        const int seg = i * 4 + wv;
        const int row = seg * 8 + r8;
        const int col = ((u ^ (row & 7)) << 2);
        async16(dst + seg * 1024, Af + (size_t)(brow + row) * K + k0 + col);
      }
    } else {
      // 8 KB: wave issue = 1 KB = 16 rows of 64 B.
      const int r4 = lane >> 2, u = lane & 3;
#pragma unroll
      for (int i = 0; i < 2; ++i) {
        const int seg = i * 4 + wv;
        const int row = seg * 16 + r4;
        const int col = ((u ^ ((row >> 1) & 3)) << 3);
        async16(dst + seg * 1024, Ab + (size_t)(brow + row) * K + k0 + col);
      }
    }
  };
  auto stageB = [&](char* dst, int k0) {
    const int r4 = lane >> 2, u = lane & 3;
#pragma unroll
    for (int i = 0; i < 2; ++i) {
      const int seg = i * 4 + wv;
      const int row = seg * 16 + r4;
      const int col = ((u ^ ((row >> 1) & 3)) << 3);
      async16(dst + seg * 1024, Bw + (size_t)(bcol + row) * K + k0 + col);
    }
  };

  const f32x4 z = {0.f, 0.f, 0.f, 0.f};
  f32x4 acc[4][4];
#pragma unroll
  for (int m = 0; m < 4; ++m)
#pragma unroll
    for (int n = 0; n < 4; ++n) acc[m][n] = z;

  const int nt = K >> 5;
  stageA(AsB[0], 0);
  stageB(BsB[0], 0);
  __syncthreads();
  int cur = 0;

  for (int tt = 0; tt < nt; ++tt) {
    // issue next tile's loads first -> latency hides under this tile's compute
    if (tt + 1 < nt) {
      stageA(AsB[cur ^ 1], (tt + 1) << 5);
      stageB(BsB[cur ^ 1], (tt + 1) << 5);
    }
    const char* Ac = AsB[cur];
    const char* Bc = BsB[cur];

    bf16x8 af[4], bfg[4];
#pragma unroll
    for (int m = 0; m < 4; ++m) {
      const int R = wm + m * 16 + fr;
      if constexpr (AF32) {
        const int xx = (R & 7) << 4;
        const f32x4 lo = *(const f32x4*)(Ac + R * 128 + ((fq << 5) ^ xx));
        const f32x4 hi = *(const f32x4*)(Ac + R * 128 + (((fq << 5) + 16) ^ xx));
        af[m] = cvt8v(lo, hi);
      } else {
        const int ph = (fq << 4) ^ (((R >> 1) & 3) << 4);
        af[m] = *(const bf16x8*)(Ac + R * 64 + ph);
      }
    }
#pragma unroll
    for (int n = 0; n < 4; ++n) {
      const int R = wn + n * 16 + fr;
      const int ph = (fq << 4) ^ (((R >> 1) & 3) << 4);
      bfg[n] = *(const bf16x8*)(Bc + R * 64 + ph);
    }
#pragma unroll
    for (int m = 0; m < 4; ++m)
#pragma unroll
      for (int n = 0; n < 4; ++n)
        acc[m][n] = __builtin_amdgcn_mfma_f32_16x16x32_bf16(af[m], bfg[n], acc[m][n], 0, 0, 0);

    __syncthreads();  // drains vmcnt(0)+lgkmcnt(0): next buffer ready, cur free
    cur ^= 1;
  }

  // epilogue: C/D layout col=lane&15, row=(lane>>4)*4+reg
  const int rb = fq * 4;
#pragma unroll
  for (int m = 0; m < 4; ++m)
#pragma unroll
    for (int n = 0; n < 4; ++n)
#pragma unroll
      for (int r = 0; r < 4; ++r) {
        const int row = brow + wm + m * 16 + rb + r;
        const int col = bcol + wn + n * 16 + fr;
        if constexpr (CF32)
          ((float*)Cp)[(size_t)row * N + col] = acc[m][n][r];
        else
          ((bf16_t*)Cp)[(size_t)row * N + col] = (__bf16)acc[m][n][r];
      }
}

// ---------------------------------------------------------------------------
// Fallback GEMM (round-1, fused f32->bf16 cvt, f32 weights) — used only if ws
// is too small for the bf16 weight buffer.
// ---------------------------------------------------------------------------
template<bool A_IS_F32, bool C_IS_F32>
__global__ __launch_bounds__(256)
void gemm_bt(const void* __restrict__ Ap, const float* __restrict__ Bw,
             void* __restrict__ Cp, int M, int N, int K) {
  (void)M;
  __shared__ bf16_t As[128][40];
  __shared__ bf16_t Bs[128][40];
  const int t = (int)threadIdx.x;
  const int lane = t & 63, wv = t >> 6;
  const int wm = (wv >> 1) * 64, wn = (wv & 1) * 64;
  const int brow = (int)blockIdx.y * 128, bcol = (int)blockIdx.x * 128;
  const int fr = lane & 15, fk = (lane >> 4) * 8;

  const f32x4 z = {0.f, 0.f, 0.f, 0.f};
  f32x4 acc[4][4];
#pragma unroll
  for (int m = 0; m < 4; ++m)
#pragma unroll
    for (int n = 0; n < 4; ++n) acc[m][n] = z;

  for (int k0 = 0; k0 < K; k0 += 32) {
    if constexpr (A_IS_F32) {
      const float* A = (const float*)Ap;
      const int tr = t >> 3, tc = (t & 7) * 4;
#pragma unroll
      for (int p = 0; p < 4; ++p) {
        const int r = p * 32 + tr;
        float4 v = *reinterpret_cast<const float4*>(A + (size_t)(brow + r) * K + k0 + tc);
        *reinterpret_cast<bf16x4*>(&As[r][tc]) = cvt4(v);
      }
    } else {
      const bf16_t* A = (const bf16_t*)Ap;
      const int tr = t >> 2, tc = (t & 3) * 8;
#pragma unroll
      for (int p = 0; p < 2; ++p) {
        const int r = p * 64 + tr;
        *reinterpret_cast<int4*>(&As[r][tc]) =
            *reinterpret_cast<const int4*>(A + (size_t)(brow + r) * K + k0 + tc);
      }
    }
    {
      const int tr = t >> 3, tc = (t & 7) * 4;
#pragma unroll
      for (int p = 0; p < 4; ++p) {
        const int r = p * 32 + tr;
        float4 v = *reinterpret_cast<const float4*>(Bw + (size_t)(bcol + r) * K + k0 + tc);
        *reinterpret_cast<bf16x4*>(&Bs[r][tc]) = cvt4(v);
      }
    }
    __syncthreads();
    bf16x8 af[4], bfr[4];
#pragma unroll
    for (int m = 0; m < 4; ++m)
      af[m] = *reinterpret_cast<const bf16x8*>(&As[wm + m * 16 + fr][fk]);
#pragma unroll
    for (int n = 0; n < 4; ++n)
      bfr[n] = *reinterpret_cast<const bf16x8*>(&Bs[wn + n * 16 + fr][fk]);
#pragma unroll
    for (int m = 0; m < 4; ++m)
#pragma unroll
      for (int n = 0; n < 4; ++n)
        acc[m][n] = __builtin_amdgcn_mfma_f32_16x16x32_bf16(af[m], bfr[n], acc[m][n], 0, 0, 0);
    __syncthreads();
  }
  const int rb = (lane >> 4) * 4;
#pragma unroll
  for (int m = 0; m < 4; ++m)
#pragma unroll
    for (int n = 0; n < 4; ++n)
#pragma unroll
      for (int r = 0; r < 4; ++r) {
        const int row = brow + wm + m * 16 + rb + r;
        const int col = bcol + wn + n * 16 + fr;
        if constexpr (C_IS_F32)
          ((float*)Cp)[(size_t)row * N + col] = acc[m][n][r];
        else
          ((bf16_t*)Cp)[(size_t)row * N + col] = (__bf16)acc[m][n][r];
      }
}

// ---------------------------------------------------------------------------
// Fused inverted attention.  Block = (b,h, l-chunk).  Softmax over the N=128
// axis is exact per l-column (fully in-tile) => l-chunks are independent.
// DIRECT: single chunk, divide by R and write bf16 ao.
// !DIRECT: write f32 partial O (cols 0..63) + partial R (col 64), stride 72.
// ---------------------------------------------------------------------------
template<bool DIRECT>
__global__ __launch_bounds__(256)
void attn_inv(const bf16_t* __restrict__ qh, const bf16_t* __restrict__ kh,
              const bf16_t* __restrict__ vh, bf16_t* __restrict__ ao,
              float* __restrict__ part, int lcount) {
  const int bh = (int)blockIdx.x;
  const int b = bh >> 4, h = bh & 15;
  const int l_begin = (int)blockIdx.y * lcount;

  __shared__ bf16_t Qs[128][72];
  __shared__ bf16_t Ks[64][72];
  __shared__ bf16_t Vt[80][72];
  __shared__ bf16_t Ps[128][72];

  const int t = (int)threadIdx.x;
  const int lane = t & 63, w = t >> 6;
  const int fr = lane & 15, fq = lane >> 4;

  const bf16_t* qb = qh + (size_t)(b * CN) * CD + h * CDh;
#pragma unroll
  for (int p = 0; p < 4; ++p) {
    const int j = p * 256 + t;
    const int r = j >> 3, cc = (j & 7) * 8;
    *reinterpret_cast<int4*>(&Qs[r][cc]) =
        *reinterpret_cast<const int4*>(qb + (size_t)r * CD + cc);
  }
#pragma unroll
  for (int p = 0; p < 4; ++p) {
    const int j = p * 256 + t;
    const int r = 64 + (j >> 6), c = j & 63;
    Vt[r][c] = (r == 64) ? (__bf16)1.0f : (__bf16)0.0f;
  }

  const f32x4 z = {0.f, 0.f, 0.f, 0.f};
  f32x4 acc[2][5];
#pragma unroll
  for (int m = 0; m < 2; ++m)
#pragma unroll
    for (int n = 0; n < 5; ++n) acc[m][n] = z;

  for (int l0 = l_begin; l0 < l_begin + lcount; l0 += 64) {
    __syncthreads();
    const bf16_t* kb = kh + (size_t)(b * CL + l0) * CD + h * CDh;
    const bf16_t* vb = vh + (size_t)(b * CL + l0) * CD + h * CDh;
#pragma unroll
    for (int p = 0; p < 2; ++p) {
      const int j = p * 256 + t;
      const int r = j >> 3, cc = (j & 7) * 8;
      *reinterpret_cast<int4*>(&Ks[r][cc]) =
          *reinterpret_cast<const int4*>(kb + (size_t)r * CD + cc);
      int4 vv = *reinterpret_cast<const int4*>(vb + (size_t)r * CD + cc);
      const bf16_t* hp = reinterpret_cast<const bf16_t*>(&vv);
#pragma unroll
      for (int i = 0; i < 8; ++i) Vt[cc + i][r] = hp[i];
    }
    __syncthreads();

    f32x4 s[8];
#pragma unroll
    for (int m = 0; m < 8; ++m) s[m] = z;
#pragma unroll
    for (int ks = 0; ks < 2; ++ks) {
      bf16x8 bk = *reinterpret_cast<const bf16x8*>(&Ks[w * 16 + fr][ks * 32 + fq * 8]);
#pragma unroll
      for (int m = 0; m < 8; ++m) {
        bf16x8 aq = *reinterpret_cast<const bf16x8*>(&Qs[m * 16 + fr][ks * 32 + fq * 8]);
        s[m] = __builtin_amdgcn_mfma_f32_16x16x32_bf16(aq, bk, s[m], 0, 0, 0);
      }
    }

    float p[8][4];
    float mx = -3.0e38f;
#pragma unroll
    for (int m = 0; m < 8; ++m)
#pragma unroll
      for (int r = 0; r < 4; ++r) {
        const float x = s[m][r] * 0.03125f;
        p[m][r] = x;
        mx = fmaxf(mx, x);
      }
    mx = fmaxf(mx, __shfl_xor(mx, 16));
    mx = fmaxf(mx, __shfl_xor(mx, 32));
    float sum = 0.f;
#pragma unroll
    for (int m = 0; m < 8; ++m)
#pragma unroll
      for (int r = 0; r < 4; ++r) {
        const float e = __expf(p[m][r] - mx);
        p[m][r] = e;
        sum += e;
      }
    sum += __shfl_xor(sum, 16);
    sum += __shfl_xor(sum, 32);
    const float inv = 1.0f / sum;
    const int pcol = w * 16 + fr;
#pragma unroll
    for (int m = 0; m < 8; ++m)
#pragma unroll
      for (int r = 0; r < 4; ++r)
        Ps[m * 16 + fq * 4 + r][pcol] = (__bf16)(p[m][r] * inv);
    __syncthreads();

#pragma unroll
    for (int ks = 0; ks < 2; ++ks) {
      bf16x8 pa[2];
#pragma unroll
      for (int m = 0; m < 2; ++m)
        pa[m] = *reinterpret_cast<const bf16x8*>(&Ps[w * 32 + m * 16 + fr][ks * 32 + fq * 8]);
#pragma unroll
      for (int n = 0; n < 5; ++n) {
        bf16x8 bv = *reinterpret_cast<const bf16x8*>(&Vt[n * 16 + fr][ks * 32 + fq * 8]);
#pragma unroll
        for (int m = 0; m < 2; ++m)
          acc[m][n] = __builtin_amdgcn_mfma_f32_16x16x32_bf16(pa[m], bv, acc[m][n], 0, 0, 0);
      }
    }
  }

  if constexpr (DIRECT) {
    bf16_t* ob = ao + (size_t)(b * CN) * CD + h * CDh;
#pragma unroll
    for (int m = 0; m < 2; ++m)
#pragma unroll
      for (int r = 0; r < 4; ++r) {
        const float R = __shfl(acc[m][4][r], lane & 48);
        const float invr = 1.0f / R;
        const int row = w * 32 + m * 16 + fq * 4 + r;
#pragma unroll
        for (int n = 0; n < 4; ++n) {
          const int col = n * 16 + fr;
          ob[(size_t)row * CD + col] = (__bf16)(acc[m][n][r] * invr);
        }
      }
  } else {
    float* pb = part + ((size_t)blockIdx.y * (CB * CH) + bh) * (size_t)(CN * 72);
#pragma unroll
    for (int m = 0; m < 2; ++m)
#pragma unroll
      for (int r = 0; r < 4; ++r) {
        const int row = w * 32 + m * 16 + fq * 4 + r;
#pragma unroll
        for (int n = 0; n < 4; ++n)
          pb[(size_t)row * 72 + n * 16 + fr] = acc[m][n][r];
        if (fr == 0) pb[(size_t)row * 72 + 64] = acc[m][4][r];
      }
  }
}

// reduce partials over splits, divide by R, write bf16 ao[b,n, h*64+c]
__global__ __launch_bounds__(256)
void attn_reduce(const float* __restrict__ part, bf16_t* __restrict__ ao, int nsplit) {
  const int idx = (int)blockIdx.x * 256 + (int)threadIdx.x;
  const int c = idx & 63;
  const int n = (idx >> 6) & 127;
  const int bh = idx >> 13;
  const float* p = part + (size_t)bh * (CN * 72) + (size_t)n * 72;
  const size_t sstr = (size_t)(CB * CH) * (CN * 72);
  float o = 0.f, r = 0.f;
  for (int s = 0; s < nsplit; ++s) {
    o += p[(size_t)s * sstr + c];
    r += p[(size_t)s * sstr + 64];
  }
  const int b = bh >> 4, h = bh & 15;
  ao[((size_t)(b * CN + n)) * CD + h * CDh + c] = (__bf16)(o / r);
}

extern "C" void kernel_launch(void* const* d_in, const int* in_sizes, int n_in,
                              void* d_out, int out_size, void* d_ws, size_t ws_size,
                              hipStream_t stream) {
  (void)in_sizes; (void)n_in; (void)out_size;
  const float* q  = (const float*)d_in[0];
  const float* k  = (const float*)d_in[1];
  const float* v  = (const float*)d_in[2];
  const float* Wq = (const float*)d_in[3];
  const float* Wk = (const float*)d_in[4];
  const float* Wv = (const float*)d_in[5];
  const float* Wo = (const float*)d_in[6];
  float* out = (float*)d_out;

  const size_t MiB = (size_t)1 << 20;
  const size_t QH_OFF = 0;
  const size_t KH_OFF = 2 * MiB;
  const size_t VH_OFF = KH_OFF + 64 * MiB;
  const size_t AO_OFF = VH_OFF + 64 * MiB;
  const size_t FIXED  = AO_OFF + 2 * MiB;  // 132 MiB (known to fit)
  if (ws_size < FIXED) return;

  char* ws = (char*)d_ws;
  bf16_t* qh = (bf16_t*)(ws + QH_OFF);
  bf16_t* kh = (bf16_t*)(ws + KH_OFF);
  bf16_t* vh = (bf16_t*)(ws + VH_OFF);
  bf16_t* ao = (bf16_t*)(ws + AO_OFF);

  const size_t extra = ws_size - FIXED;
  const bool newgemm = extra >= 2 * MiB;              // room for bf16 weight buf
  bf16_t* wbuf = (bf16_t*)(ws + FIXED);
  const size_t PB = (size_t)CB * CH * CN * 72 * 4;    // 4,718,592 B per split
  const size_t pav = newgemm ? (extra - 2 * MiB) : 0;
  int nsplit = 8;
  while (nsplit > 1 && (size_t)nsplit * PB > pav) nsplit >>= 1;
  float* part = (float*)(ws + FIXED + 2 * MiB);

  const int M_q = CB * CN;    // 1024
  const int M_kv = CB * CL;   // 32768
  const int W4 = CD * CD / 4; // 262144 float4s per weight

  if (newgemm) {
    cvt_f32_bf16<<<W4 / 256, 256, 0, stream>>>(Wq, wbuf, W4);
    gemm_dma<true, false><<<(M_q / 128) * 8, 256, 0, stream>>>(q, wbuf, qh, M_q / 128, CD, CD);
    cvt_f32_bf16<<<W4 / 256, 256, 0, stream>>>(Wk, wbuf, W4);
    gemm_dma<true, false><<<(M_kv / 128) * 8, 256, 0, stream>>>(k, wbuf, kh, M_kv / 128, CD, CD);
    cvt_f32_bf16<<<W4 / 256, 256, 0, stream>>>(Wv, wbuf, W4);
    gemm_dma<true, false><<<(M_kv / 128) * 8, 256, 0, stream>>>(v, wbuf, vh, M_kv / 128, CD, CD);
  } else {
    gemm_bt<true, false><<<dim3(CD / 128, M_q / 128),  256, 0, stream>>>(q, Wq, qh, M_q,  CD, CD);
    gemm_bt<true, false><<<dim3(CD / 128, M_kv / 128), 256, 0, stream>>>(k, Wk, kh, M_kv, CD, CD);
    gemm_bt<true, false><<<dim3(CD / 128, M_kv / 128), 256, 0, stream>>>(v, Wv, vh, M_kv, CD, CD);
  }

  if (nsplit > 1) {
    attn_inv<false><<<dim3(CB * CH, nsplit), 256, 0, stream>>>(qh, kh, vh, ao, part, CL / nsplit);
    attn_reduce<<<(CB * CH * CN * 64) / 256, 256, 0, stream>>>(part, ao, nsplit);
  } else {
    attn_inv<true><<<dim3(CB * CH, 1), 256, 0, stream>>>(qh, kh, vh, ao, nullptr, CL);
  }

  if (newgemm) {
    cvt_f32_bf16<<<W4 / 256, 256, 0, stream>>>(Wo, wbuf, W4);
    gemm_dma<false, true><<<(M_q / 128) * 8, 256, 0, stream>>>(ao, wbuf, out, M_q / 128, CD, CD);
  } else {
    gemm_bt<false, true><<<dim3(CD / 128, M_q / 128), 256, 0, stream>>>(ao, Wo, out, M_q, CD, CD);
  }
}

// Round 5
// 368.688 us; speedup vs baseline: 1.6017x; 1.1219x over previous
//
#include <hip/hip_runtime.h>
#include <stdint.h>

typedef __bf16 bf16_t;
typedef __bf16 bf16x4 __attribute__((ext_vector_type(4)));
typedef __bf16 bf16x8 __attribute__((ext_vector_type(8)));
typedef float f32x4 __attribute__((ext_vector_type(4)));
typedef unsigned int u32;

// Problem constants (B, N, L, D, H) = (8, 128, 4096, 1024, 16)
constexpr int CB = 8, CN = 128, CL = 4096, CD = 1024, CH = 16, CDh = 64;

__device__ __forceinline__ bf16x4 cvt4(float4 v) {
  bf16x4 r;
  r[0] = (__bf16)v.x; r[1] = (__bf16)v.y; r[2] = (__bf16)v.z; r[3] = (__bf16)v.w;
  return r;
}
__device__ __forceinline__ bf16x8 cvt8v(f32x4 lo, f32x4 hi) {
  bf16x8 r;
#pragma unroll
  for (int i = 0; i < 4; ++i) { r[i] = (__bf16)lo[i]; r[i + 4] = (__bf16)hi[i]; }
  return r;
}

// async global->LDS, 16 B per lane. LDS dest is wave-uniform base + lane*16.
__device__ __forceinline__ void async16(void* lds, const void* g) {
  __builtin_amdgcn_global_load_lds(
      (const __attribute__((address_space(1))) u32*)g,
      (__attribute__((address_space(3))) u32*)lds, 16, 0, 0);
}

// f32 -> bf16 elementwise, n4 = elems/4
__global__ __launch_bounds__(256) void cvt_f32_bf16(const float* __restrict__ in,
                                                    bf16_t* __restrict__ outp, int n4) {
  int i = (int)blockIdx.x * 256 + (int)threadIdx.x;
  if (i < n4) {
    float4 v = reinterpret_cast<const float4*>(in)[i];
    reinterpret_cast<bf16x4*>(outp)[i] = cvt4(v);
  }
}

// ---------------------------------------------------------------------------
// DMA-staged GEMM, 2-phase double-buffered K-loop.
// C[M,N] = A[M,K] @ Wb[N,K]^T.  A f32 (AF32) or bf16; Wb always bf16.
// 128x128 tile, BK=32, 4 waves, global_load_lds width-16, source-side XOR
// swizzle (linear DMA dest + pre-swizzled global src + swizzled ds_read).
// Round-5: preferred path is AF32=false (bf16 A from a cvt prepass) — halves
// the LDS-read pipe cost (8 ds_read_b128/wave-step vs 12) which round-4
// profiling showed to be the binding resource (MfmaUtil 17%, VALUBusy 19%,
// BW 12% => LDS-pipe-bound).
// XCD mapping: bid%8 = XCD; each XCD owns a distinct M-stripe, 8 N-blocks
// innermost (A panel + W L2-locality best-effort).
// ---------------------------------------------------------------------------
template<bool AF32, bool CF32>
__global__ __launch_bounds__(256)
void gemm_dma(const void* __restrict__ Ap, const bf16_t* __restrict__ Bw,
              void* __restrict__ Cp, int mblocks, int N, int K) {
  constexpr int ASZ = AF32 ? 16384 : 8192;
  __shared__ __attribute__((aligned(16))) char AsB[2][ASZ];
  __shared__ __attribute__((aligned(16))) char BsB[2][8192];

  const int t = (int)threadIdx.x;
  const int lane = t & 63, wv = t >> 6;
  const int bid = (int)blockIdx.x;
  const int x = bid & 7;            // XCD id (dispatch round-robin)
  const int j = bid >> 3;           // sequence index within XCD
  const int S = mblocks >> 3;       // M-blocks per XCD stripe
  const int mb = (S > 0) ? (x * S + (j >> 3)) : (j >> 3);
  const int nb = j & 7;             // N-block innermost
  const int brow = mb * 128;
  const int bcol = nb * 128;
  const int wm = (wv >> 1) * 64, wn = (wv & 1) * 64;
  const int fr = lane & 15, fq = lane >> 4;

  const float*  Af = (const float*)Ap;
  const bf16_t* Ab = (const bf16_t*)Ap;

  auto stageA = [&](char* dst, int k0) {
    if constexpr (AF32) {
      const int r8 = lane >> 3, u = lane & 7;
#pragma unroll
      for (int i = 0; i < 4; ++i) {
        const int seg = i * 4 + wv;
        const int row = seg * 8 + r8;
        const int col = ((u ^ (row & 7)) << 2);
        async16(dst + seg * 1024, Af + (size_t)(brow + row) * K + k0 + col);
      }
    } else {
      const int r4 = lane >> 2, u = lane & 3;
#pragma unroll
      for (int i = 0; i < 2; ++i) {
        const int seg = i * 4 + wv;
        const int row = seg * 16 + r4;
        const int col = ((u ^ ((row >> 1) & 3)) << 3);
        async16(dst + seg * 1024, Ab + (size_t)(brow + row) * K + k0 + col);
      }
    }
  };
  auto stageB = [&](char* dst, int k0) {
    const int r4 = lane >> 2, u = lane & 3;
#pragma unroll
    for (int i = 0; i < 2; ++i) {
      const int seg = i * 4 + wv;
      const int row = seg * 16 + r4;
      const int col = ((u ^ ((row >> 1) & 3)) << 3);
      async16(dst + seg * 1024, Bw + (size_t)(bcol + row) * K + k0 + col);
    }
  };

  const f32x4 z = {0.f, 0.f, 0.f, 0.f};
  f32x4 acc[4][4];
#pragma unroll
  for (int m = 0; m < 4; ++m)
#pragma unroll
    for (int n = 0; n < 4; ++n) acc[m][n] = z;

  const int nt = K >> 5;
  stageA(AsB[0], 0);
  stageB(BsB[0], 0);
  __syncthreads();
  int cur = 0;

  for (int tt = 0; tt < nt; ++tt) {
    if (tt + 1 < nt) {
      stageA(AsB[cur ^ 1], (tt + 1) << 5);
      stageB(BsB[cur ^ 1], (tt + 1) << 5);
    }
    const char* Ac = AsB[cur];
    const char* Bc = BsB[cur];

    bf16x8 af[4], bfg[4];
#pragma unroll
    for (int m = 0; m < 4; ++m) {
      const int R = wm + m * 16 + fr;
      if constexpr (AF32) {
        const int xx = (R & 7) << 4;
        const f32x4 lo = *(const f32x4*)(Ac + R * 128 + ((fq << 5) ^ xx));
        const f32x4 hi = *(const f32x4*)(Ac + R * 128 + (((fq << 5) + 16) ^ xx));
        af[m] = cvt8v(lo, hi);
      } else {
        const int ph = (fq << 4) ^ (((R >> 1) & 3) << 4);
        af[m] = *(const bf16x8*)(Ac + R * 64 + ph);
      }
    }
#pragma unroll
    for (int n = 0; n < 4; ++n) {
      const int R = wn + n * 16 + fr;
      const int ph = (fq << 4) ^ (((R >> 1) & 3) << 4);
      bfg[n] = *(const bf16x8*)(Bc + R * 64 + ph);
    }
#pragma unroll
    for (int m = 0; m < 4; ++m)
#pragma unroll
      for (int n = 0; n < 4; ++n)
        acc[m][n] = __builtin_amdgcn_mfma_f32_16x16x32_bf16(af[m], bfg[n], acc[m][n], 0, 0, 0);

    __syncthreads();  // drains vmcnt+lgkmcnt: next buffer ready, cur free
    cur ^= 1;
  }

  // epilogue: C/D layout col=lane&15, row=(lane>>4)*4+reg
  const int rb = fq * 4;
#pragma unroll
  for (int m = 0; m < 4; ++m)
#pragma unroll
    for (int n = 0; n < 4; ++n)
#pragma unroll
      for (int r = 0; r < 4; ++r) {
        const int row = brow + wm + m * 16 + rb + r;
        const int col = bcol + wn + n * 16 + fr;
        if constexpr (CF32)
          ((float*)Cp)[(size_t)row * N + col] = acc[m][n][r];
        else
          ((bf16_t*)Cp)[(size_t)row * N + col] = (__bf16)acc[m][n][r];
      }
}

// ---------------------------------------------------------------------------
// Fallback GEMM (round-1, fused f32->bf16 cvt, f32 weights) — used only if ws
// is too small for the bf16 weight buffer.
// ---------------------------------------------------------------------------
template<bool A_IS_F32, bool C_IS_F32>
__global__ __launch_bounds__(256)
void gemm_bt(const void* __restrict__ Ap, const float* __restrict__ Bw,
             void* __restrict__ Cp, int M, int N, int K) {
  (void)M;
  __shared__ bf16_t As[128][40];
  __shared__ bf16_t Bs[128][40];
  const int t = (int)threadIdx.x;
  const int lane = t & 63, wv = t >> 6;
  const int wm = (wv >> 1) * 64, wn = (wv & 1) * 64;
  const int brow = (int)blockIdx.y * 128, bcol = (int)blockIdx.x * 128;
  const int fr = lane & 15, fk = (lane >> 4) * 8;

  const f32x4 z = {0.f, 0.f, 0.f, 0.f};
  f32x4 acc[4][4];
#pragma unroll
  for (int m = 0; m < 4; ++m)
#pragma unroll
    for (int n = 0; n < 4; ++n) acc[m][n] = z;

  for (int k0 = 0; k0 < K; k0 += 32) {
    if constexpr (A_IS_F32) {
      const float* A = (const float*)Ap;
      const int tr = t >> 3, tc = (t & 7) * 4;
#pragma unroll
      for (int p = 0; p < 4; ++p) {
        const int r = p * 32 + tr;
        float4 v = *reinterpret_cast<const float4*>(A + (size_t)(brow + r) * K + k0 + tc);
        *reinterpret_cast<bf16x4*>(&As[r][tc]) = cvt4(v);
      }
    } else {
      const bf16_t* A = (const bf16_t*)Ap;
      const int tr = t >> 2, tc = (t & 3) * 8;
#pragma unroll
      for (int p = 0; p < 2; ++p) {
        const int r = p * 64 + tr;
        *reinterpret_cast<int4*>(&As[r][tc]) =
            *reinterpret_cast<const int4*>(A + (size_t)(brow + r) * K + k0 + tc);
      }
    }
    {
      const int tr = t >> 3, tc = (t & 7) * 4;
#pragma unroll
      for (int p = 0; p < 4; ++p) {
        const int r = p * 32 + tr;
        float4 v = *reinterpret_cast<const float4*>(Bw + (size_t)(bcol + r) * K + k0 + tc);
        *reinterpret_cast<bf16x4*>(&Bs[r][tc]) = cvt4(v);
      }
    }
    __syncthreads();
    bf16x8 af[4], bfr[4];
#pragma unroll
    for (int m = 0; m < 4; ++m)
      af[m] = *reinterpret_cast<const bf16x8*>(&As[wm + m * 16 + fr][fk]);
#pragma unroll
    for (int n = 0; n < 4; ++n)
      bfr[n] = *reinterpret_cast<const bf16x8*>(&Bs[wn + n * 16 + fr][fk]);
#pragma unroll
    for (int m = 0; m < 4; ++m)
#pragma unroll
      for (int n = 0; n < 4; ++n)
        acc[m][n] = __builtin_amdgcn_mfma_f32_16x16x32_bf16(af[m], bfr[n], acc[m][n], 0, 0, 0);
    __syncthreads();
  }
  const int rb = (lane >> 4) * 4;
#pragma unroll
  for (int m = 0; m < 4; ++m)
#pragma unroll
    for (int n = 0; n < 4; ++n)
#pragma unroll
      for (int r = 0; r < 4; ++r) {
        const int row = brow + wm + m * 16 + rb + r;
        const int col = bcol + wn + n * 16 + fr;
        if constexpr (C_IS_F32)
          ((float*)Cp)[(size_t)row * N + col] = acc[m][n][r];
        else
          ((bf16_t*)Cp)[(size_t)row * N + col] = (__bf16)acc[m][n][r];
      }
}

// ---------------------------------------------------------------------------
// Fused inverted attention.  Block = (b,h, l-chunk).  Softmax over the N=128
// axis is exact per l-column (fully in-tile) => l-chunks are independent.
// DIRECT: single chunk, divide by R and write bf16 ao.
// !DIRECT: write f32 partial O (cols 0..63) + partial R (col 64), stride 72.
// ---------------------------------------------------------------------------
template<bool DIRECT>
__global__ __launch_bounds__(256)
void attn_inv(const bf16_t* __restrict__ qh, const bf16_t* __restrict__ kh,
              const bf16_t* __restrict__ vh, bf16_t* __restrict__ ao,
              float* __restrict__ part, int lcount) {
  const int bh = (int)blockIdx.x;
  const int b = bh >> 4, h = bh & 15;
  const int l_begin = (int)blockIdx.y * lcount;

  __shared__ bf16_t Qs[128][72];
  __shared__ bf16_t Ks[64][72];
  __shared__ bf16_t Vt[80][72];
  __shared__ bf16_t Ps[128][72];

  const int t = (int)threadIdx.x;
  const int lane = t & 63, w = t >> 6;
  const int fr = lane & 15, fq = lane >> 4;

  const bf16_t* qb = qh + (size_t)(b * CN) * CD + h * CDh;
#pragma unroll
  for (int p = 0; p < 4; ++p) {
    const int j = p * 256 + t;
    const int r = j >> 3, cc = (j & 7) * 8;
    *reinterpret_cast<int4*>(&Qs[r][cc]) =
        *reinterpret_cast<const int4*>(qb + (size_t)r * CD + cc);
  }
#pragma unroll
  for (int p = 0; p < 4; ++p) {
    const int j = p * 256 + t;
    const int r = 64 + (j >> 6), c = j & 63;
    Vt[r][c] = (r == 64) ? (__bf16)1.0f : (__bf16)0.0f;
  }

  const f32x4 z = {0.f, 0.f, 0.f, 0.f};
  f32x4 acc[2][5];
#pragma unroll
  for (int m = 0; m < 2; ++m)
#pragma unroll
    for (int n = 0; n < 5; ++n) acc[m][n] = z;

  for (int l0 = l_begin; l0 < l_begin + lcount; l0 += 64) {
    __syncthreads();
    const bf16_t* kb = kh + (size_t)(b * CL + l0) * CD + h * CDh;
    const bf16_t* vb = vh + (size_t)(b * CL + l0) * CD + h * CDh;
#pragma unroll
    for (int p = 0; p < 2; ++p) {
      const int j = p * 256 + t;
      const int r = j >> 3, cc = (j & 7) * 8;
      *reinterpret_cast<int4*>(&Ks[r][cc]) =
          *reinterpret_cast<const int4*>(kb + (size_t)r * CD + cc);
      int4 vv = *reinterpret_cast<const int4*>(vb + (size_t)r * CD + cc);
      const bf16_t* hp = reinterpret_cast<const bf16_t*>(&vv);
#pragma unroll
      for (int i = 0; i < 8; ++i) Vt[cc + i][r] = hp[i];
    }
    __syncthreads();

    f32x4 s[8];
#pragma unroll
    for (int m = 0; m < 8; ++m) s[m] = z;
#pragma unroll
    for (int ks = 0; ks < 2; ++ks) {
      bf16x8 bk = *reinterpret_cast<const bf16x8*>(&Ks[w * 16 + fr][ks * 32 + fq * 8]);
#pragma unroll
      for (int m = 0; m < 8; ++m) {
        bf16x8 aq = *reinterpret_cast<const bf16x8*>(&Qs[m * 16 + fr][ks * 32 + fq * 8]);
        s[m] = __builtin_amdgcn_mfma_f32_16x16x32_bf16(aq, bk, s[m], 0, 0, 0);
      }
    }

    float p[8][4];
    float mx = -3.0e38f;
#pragma unroll
    for (int m = 0; m < 8; ++m)
#pragma unroll
      for (int r = 0; r < 4; ++r) {
        const float x = s[m][r] * 0.03125f;
        p[m][r] = x;
        mx = fmaxf(mx, x);
      }
    mx = fmaxf(mx, __shfl_xor(mx, 16));
    mx = fmaxf(mx, __shfl_xor(mx, 32));
    float sum = 0.f;
#pragma unroll
    for (int m = 0; m < 8; ++m)
#pragma unroll
      for (int r = 0; r < 4; ++r) {
        const float e = __expf(p[m][r] - mx);
        p[m][r] = e;
        sum += e;
      }
    sum += __shfl_xor(sum, 16);
    sum += __shfl_xor(sum, 32);
    const float inv = 1.0f / sum;
    const int pcol = w * 16 + fr;
#pragma unroll
    for (int m = 0; m < 8; ++m)
#pragma unroll
      for (int r = 0; r < 4; ++r)
        Ps[m * 16 + fq * 4 + r][pcol] = (__bf16)(p[m][r] * inv);
    __syncthreads();

#pragma unroll
    for (int ks = 0; ks < 2; ++ks) {
      bf16x8 pa[2];
#pragma unroll
      for (int m = 0; m < 2; ++m)
        pa[m] = *reinterpret_cast<const bf16x8*>(&Ps[w * 32 + m * 16 + fr][ks * 32 + fq * 8]);
#pragma unroll
      for (int n = 0; n < 5; ++n) {
        bf16x8 bv = *reinterpret_cast<const bf16x8*>(&Vt[n * 16 + fr][ks * 32 + fq * 8]);
#pragma unroll
        for (int m = 0; m < 2; ++m)
          acc[m][n] = __builtin_amdgcn_mfma_f32_16x16x32_bf16(pa[m], bv, acc[m][n], 0, 0, 0);
      }
    }
  }

  if constexpr (DIRECT) {
    bf16_t* ob = ao + (size_t)(b * CN) * CD + h * CDh;
#pragma unroll
    for (int m = 0; m < 2; ++m)
#pragma unroll
      for (int r = 0; r < 4; ++r) {
        const float R = __shfl(acc[m][4][r], lane & 48);
        const float invr = 1.0f / R;
        const int row = w * 32 + m * 16 + fq * 4 + r;
#pragma unroll
        for (int n = 0; n < 4; ++n) {
          const int col = n * 16 + fr;
          ob[(size_t)row * CD + col] = (__bf16)(acc[m][n][r] * invr);
        }
      }
  } else {
    float* pb = part + ((size_t)blockIdx.y * (CB * CH) + bh) * (size_t)(CN * 72);
#pragma unroll
    for (int m = 0; m < 2; ++m)
#pragma unroll
      for (int r = 0; r < 4; ++r) {
        const int row = w * 32 + m * 16 + fq * 4 + r;
#pragma unroll
        for (int n = 0; n < 4; ++n)
          pb[(size_t)row * 72 + n * 16 + fr] = acc[m][n][r];
        if (fr == 0) pb[(size_t)row * 72 + 64] = acc[m][4][r];
      }
  }
}

// reduce partials over splits, divide by R, write bf16 ao[b,n, h*64+c]
__global__ __launch_bounds__(256)
void attn_reduce(const float* __restrict__ part, bf16_t* __restrict__ ao, int nsplit) {
  const int idx = (int)blockIdx.x * 256 + (int)threadIdx.x;
  const int c = idx & 63;
  const int n = (idx >> 6) & 127;
  const int bh = idx >> 13;
  const float* p = part + (size_t)bh * (CN * 72) + (size_t)n * 72;
  const size_t sstr = (size_t)(CB * CH) * (CN * 72);
  float o = 0.f, r = 0.f;
  for (int s = 0; s < nsplit; ++s) {
    o += p[(size_t)s * sstr + c];
    r += p[(size_t)s * sstr + 64];
  }
  const int b = bh >> 4, h = bh & 15;
  ao[((size_t)(b * CN + n)) * CD + h * CDh + c] = (__bf16)(o / r);
}

extern "C" void kernel_launch(void* const* d_in, const int* in_sizes, int n_in,
                              void* d_out, int out_size, void* d_ws, size_t ws_size,
                              hipStream_t stream) {
  (void)in_sizes; (void)n_in; (void)out_size;
  const float* q  = (const float*)d_in[0];
  const float* k  = (const float*)d_in[1];
  const float* v  = (const float*)d_in[2];
  const float* Wq = (const float*)d_in[3];
  const float* Wk = (const float*)d_in[4];
  const float* Wv = (const float*)d_in[5];
  const float* Wo = (const float*)d_in[6];
  float* out = (float*)d_out;

  const size_t MiB = (size_t)1 << 20;
  const size_t QH_OFF = 0;
  const size_t KH_OFF = 2 * MiB;
  const size_t VH_OFF = KH_OFF + 64 * MiB;
  const size_t AO_OFF = VH_OFF + 64 * MiB;
  const size_t FIXED  = AO_OFF + 2 * MiB;  // 132 MiB (known to fit)
  if (ws_size < FIXED) return;

  char* ws = (char*)d_ws;
  bf16_t* qh = (bf16_t*)(ws + QH_OFF);
  bf16_t* kh = (bf16_t*)(ws + KH_OFF);
  bf16_t* vh = (bf16_t*)(ws + VH_OFF);
  bf16_t* ao = (bf16_t*)(ws + AO_OFF);

  const int M_q = CB * CN;    // 1024
  const int M_kv = CB * CL;   // 32768
  const int W4 = CD * CD / 4; // 262144 float4s per weight
  const int A4_kv = M_kv * CD / 4;  // 8,388,608 float4s (k or v)
  const int A4_q  = M_q * CD / 4;   // 262,144

  const size_t WBUF_OFF = FIXED;            // 2 MiB bf16 weights
  const size_t QC_OFF   = WBUF_OFF + 2 * MiB;  // 2 MiB bf16 q
  const size_t KC_OFF   = QC_OFF + 2 * MiB;    // 64 MiB bf16 k (reused for v; part aliases)
  const size_t NEED_FAST = KC_OFF + 64 * MiB;  // 200 MiB

  const size_t PB = (size_t)CB * CH * CN * 72 * 4;  // 4,718,592 B per split

  if (ws_size >= NEED_FAST) {
    // -------- fast path: all-bf16 GEMMs via cvt prepass --------
    bf16_t* wbuf = (bf16_t*)(ws + WBUF_OFF);
    bf16_t* qc   = (bf16_t*)(ws + QC_OFF);
    bf16_t* kc   = (bf16_t*)(ws + KC_OFF);
    float*  part = (float*)(ws + KC_OFF);   // aliases kc (dead after its GEMM)

    cvt_f32_bf16<<<A4_q / 256, 256, 0, stream>>>(q, qc, A4_q);
    cvt_f32_bf16<<<W4 / 256, 256, 0, stream>>>(Wq, wbuf, W4);
    gemm_dma<false, false><<<(M_q / 128) * 8, 256, 0, stream>>>(qc, wbuf, qh, M_q / 128, CD, CD);

    cvt_f32_bf16<<<A4_kv / 256, 256, 0, stream>>>(k, kc, A4_kv);
    cvt_f32_bf16<<<W4 / 256, 256, 0, stream>>>(Wk, wbuf, W4);
    gemm_dma<false, false><<<(M_kv / 128) * 8, 256, 0, stream>>>(kc, wbuf, kh, M_kv / 128, CD, CD);

    cvt_f32_bf16<<<A4_kv / 256, 256, 0, stream>>>(v, kc, A4_kv);   // reuse kc
    cvt_f32_bf16<<<W4 / 256, 256, 0, stream>>>(Wv, wbuf, W4);
    gemm_dma<false, false><<<(M_kv / 128) * 8, 256, 0, stream>>>(kc, wbuf, vh, M_kv / 128, CD, CD);

    // kc now dead -> part (8 splits x 4.5 MiB = 36 MiB <= 64 MiB)
    attn_inv<false><<<dim3(CB * CH, 8), 256, 0, stream>>>(qh, kh, vh, ao, part, CL / 8);
    attn_reduce<<<(CB * CH * CN * 64) / 256, 256, 0, stream>>>(part, ao, 8);

    cvt_f32_bf16<<<W4 / 256, 256, 0, stream>>>(Wo, wbuf, W4);
    gemm_dma<false, true><<<(M_q / 128) * 8, 256, 0, stream>>>(ao, wbuf, out, M_q / 128, CD, CD);
    return;
  }

  // -------- fallback (round-4 behavior) --------
  const size_t extra = ws_size - FIXED;
  const bool newgemm = extra >= 2 * MiB;
  bf16_t* wbuf = (bf16_t*)(ws + FIXED);
  const size_t pav = newgemm ? (extra - 2 * MiB) : 0;
  int nsplit = 8;
  while (nsplit > 1 && (size_t)nsplit * PB > pav) nsplit >>= 1;
  float* part = (float*)(ws + FIXED + 2 * MiB);

  if (newgemm) {
    cvt_f32_bf16<<<W4 / 256, 256, 0, stream>>>(Wq, wbuf, W4);
    gemm_dma<true, false><<<(M_q / 128) * 8, 256, 0, stream>>>(q, wbuf, qh, M_q / 128, CD, CD);
    cvt_f32_bf16<<<W4 / 256, 256, 0, stream>>>(Wk, wbuf, W4);
    gemm_dma<true, false><<<(M_kv / 128) * 8, 256, 0, stream>>>(k, wbuf, kh, M_kv / 128, CD, CD);
    cvt_f32_bf16<<<W4 / 256, 256, 0, stream>>>(Wv, wbuf, W4);
    gemm_dma<true, false><<<(M_kv / 128) * 8, 256, 0, stream>>>(v, wbuf, vh, M_kv / 128, CD, CD);
  } else {
    gemm_bt<true, false><<<dim3(CD / 128, M_q / 128),  256, 0, stream>>>(q, Wq, qh, M_q,  CD, CD);
    gemm_bt<true, false><<<dim3(CD / 128, M_kv / 128), 256, 0, stream>>>(k, Wk, kh, M_kv, CD, CD);
    gemm_bt<true, false><<<dim3(CD / 128, M_kv / 128), 256, 0, stream>>>(v, Wv, vh, M_kv, CD, CD);
  }

  if (nsplit > 1) {
    attn_inv<false><<<dim3(CB * CH, nsplit), 256, 0, stream>>>(qh, kh, vh, ao, part, CL / nsplit);
    attn_reduce<<<(CB * CH * CN * 64) / 256, 256, 0, stream>>>(part, ao, nsplit);
  } else {
    attn_inv<true><<<dim3(CB * CH, 1), 256, 0, stream>>>(qh, kh, vh, ao, nullptr, CL);
  }

  if (newgemm) {
    cvt_f32_bf16<<<W4 / 256, 256, 0, stream>>>(Wo, wbuf, W4);
    gemm_dma<false, true><<<(M_q / 128) * 8, 256, 0, stream>>>(ao, wbuf, out, M_q / 128, CD, CD);
  } else {
    gemm_bt<false, true><<<dim3(CD / 128, M_q / 128), 256, 0, stream>>>(ao, Wo, out, M_q, CD, CD);
  }
}